// Round 8
// baseline (439.319 us; speedup 1.0000x reference)
//
#include <hip/hip_runtime.h>
#include <hip/hip_bf16.h>
#include <hip/hip_fp16.h>

// GAT 3-layer (PPI-style) on MI355X. fp32 tensors; edge_index (2,E) planar,
// int32/int64 via device flag. R16 -> R17:
// agg was latency/request-bound: 850K gather instructions at ~33cyc each,
// nothing saturated (HBM 16%, VALU 42%, L2 7%). fp16 rows = 128B = 64 halves,
// so one 64-lane load can cover TWO rows: lane = r*32+c2 loads __half2 of
// edge (k+r). agg v4: 16-edge chunks, 8 gather instrs/chunk (2x edges in
// flight, 0.5 instr/edge), p broadcast via bpermute, r-halves combined with
// shfl_xor(32). Invalid edges carry p=0 so clamped loads contribute nothing.

#define CH 4096     // items per partition block
#define CAP 8192    // csrD staging capacity (mean bucket = 4352, 60 sigma headroom)

__device__ __forceinline__ float lrelu(float s) { return (s >= 0.f) ? s : 0.2f * s; }

// ---------------- edge dtype detection: (2,E) planar ----------------

__global__ void detect_kernel(const int* __restrict__ ei, int* __restrict__ flag) {
    int t = threadIdx.x;  // 64 lanes
    int v = ei[2 * t + 1];
    unsigned long long b = __ballot(v == 0);
    if (t == 0) *flag = (b == ~0ULL) ? 1 : 0;
}

__device__ __forceinline__ int edge_at(const void* ei, int is64, long long idx) {
    return is64 ? (int)((const long long*)ei)[idx] : ((const int*)ei)[idx];
}

// ---------------- bucketed CSR build ----------------

__global__ void zero_btot_kernel(int* __restrict__ btot) {
    btot[threadIdx.x] = 0;  // 256 threads
}

__global__ __launch_bounds__(256)
void histA_kernel(const void* __restrict__ ei, const int* __restrict__ flag,
                  int* __restrict__ blkhist, int* __restrict__ btot, int E, int N) {
    __shared__ int h[256];
    int t = threadIdx.x;
    h[t] = 0;
    __syncthreads();
    int is64 = *flag;
    long long base = (long long)blockIdx.x * CH;
    long long tot = (long long)E + N;
#pragma unroll
    for (int i = 0; i < CH / 256; ++i) {
        long long idx = base + t + i * 256;
        if (idx < tot) {
            int dst = (idx < E) ? edge_at(ei, is64, (long long)E + idx) : (int)(idx - E);
            atomicAdd(&h[(dst >> 8) & 255], 1);
        }
    }
    __syncthreads();
    int nb = (N + 255) >> 8;
    if (t < nb) {
        blkhist[t * 256 + blockIdx.x] = h[t];
        atomicAdd(&btot[t], h[t]);
    }
}

__global__ __launch_bounds__(256)
void bucket_scan_kernel(const int* __restrict__ btot, int* __restrict__ bbase,
                        int nb, int total) {
    __shared__ int s[256];
    int t = threadIdx.x;
    int v = (t < nb) ? btot[t] : 0;
    s[t] = v;
    __syncthreads();
#pragma unroll
    for (int off = 1; off < 256; off <<= 1) {
        int u = (t >= off) ? s[t - off] : 0;
        __syncthreads();
        s[t] += u;
        __syncthreads();
    }
    if (t < nb) bbase[t] = s[t] - v;
    if (t == 0) bbase[nb] = total;
}

__global__ __launch_bounds__(256)
void blk_scan_kernel(const int* __restrict__ blkhist, const int* __restrict__ bbase,
                     int* __restrict__ blkoff, int nblk) {
    __shared__ int s[256];
    int t = threadIdx.x;
    int b = blockIdx.x;
    int v = (t < nblk) ? blkhist[b * 256 + t] : 0;
    s[t] = v;
    __syncthreads();
#pragma unroll
    for (int off = 1; off < 256; off <<= 1) {
        int u = (t >= off) ? s[t - off] : 0;
        __syncthreads();
        s[t] += u;
        __syncthreads();
    }
    if (t < nblk) blkoff[b * 256 + t] = bbase[b] + s[t] - v;
}

__global__ __launch_bounds__(256)
void partC_kernel(const void* __restrict__ ei, const int* __restrict__ flag,
                  const int* __restrict__ blkoff, int2* __restrict__ part,
                  int E, int N) {
    __shared__ int h[256];
    __shared__ int lst[256];
    __shared__ int cur[256];
    __shared__ int grb[256];
    __shared__ int ssrc[CH];
    __shared__ int sdst[CH];
    int t = threadIdx.x;
    h[t] = 0;
    __syncthreads();
    int is64 = *flag;
    long long base = (long long)blockIdx.x * CH;
    long long tot = (long long)E + N;
    int msrc[CH / 256], mdst[CH / 256], mb[CH / 256];
#pragma unroll
    for (int i = 0; i < CH / 256; ++i) {
        long long idx = base + t + i * 256;
        if (idx < tot) {
            int s, d;
            if (idx < E) {
                s = edge_at(ei, is64, idx);
                d = edge_at(ei, is64, (long long)E + idx);
            } else {
                s = (int)(idx - E);
                d = s;
            }
            msrc[i] = s;
            mdst[i] = d;
            mb[i] = (d >> 8) & 255;
            atomicAdd(&h[mb[i]], 1);
        } else {
            mb[i] = -1;
        }
    }
    __syncthreads();
    int v = h[t];
    lst[t] = v;
    __syncthreads();
#pragma unroll
    for (int off = 1; off < 256; off <<= 1) {
        int u = (t >= off) ? lst[t - off] : 0;
        __syncthreads();
        lst[t] += u;
        __syncthreads();
    }
    int ex = lst[t] - v;
    lst[t] = ex;
    cur[t] = ex;
    int nb = (N + 255) >> 8;
    grb[t] = (t < nb) ? blkoff[t * 256 + blockIdx.x] : 0;
    __syncthreads();
#pragma unroll
    for (int i = 0; i < CH / 256; ++i) {
        if (mb[i] >= 0) {
            int slot = atomicAdd(&cur[mb[i]], 1);
            ssrc[slot] = msrc[i];
            sdst[slot] = mdst[i];
        }
    }
    __syncthreads();
    int items = (int)((tot - base < CH) ? (tot - base) : CH);
    for (int r = t; r < items; r += 256) {
        int d = sdst[r];
        int b = (d >> 8) & 255;
        part[grb[b] + (r - lst[b])] = make_int2(ssrc[r], d);
    }
}

__global__ __launch_bounds__(256)
void csrD_kernel(const int2* __restrict__ part, const int* __restrict__ bbase,
                 int* __restrict__ row_ptr, int* __restrict__ adj, int N) {
    __shared__ int cnt[256];
    __shared__ int lst[256];
    __shared__ int cur[256];
    __shared__ int ssrc[CAP];
    int t = threadIdx.x;
    int b = blockIdx.x;
    int lo = bbase[b], hi = bbase[b + 1];
    int n0 = b << 8;
    cnt[t] = 0;
    __syncthreads();
    for (int r = lo + t; r < hi; r += 256) atomicAdd(&cnt[part[r].y & 255], 1);
    __syncthreads();
    int v = cnt[t];
    lst[t] = v;
    __syncthreads();
#pragma unroll
    for (int off = 1; off < 256; off <<= 1) {
        int u = (t >= off) ? lst[t - off] : 0;
        __syncthreads();
        lst[t] += u;
        __syncthreads();
    }
    int ex = lst[t] - v;
    lst[t] = ex;
    cur[t] = ex;
    __syncthreads();
    if (n0 + t < N) row_ptr[n0 + t] = lo + ex;
    if (b == gridDim.x - 1 && t == 0) row_ptr[N] = hi;
    int items = hi - lo;
    if (items <= CAP) {
        for (int r = lo + t; r < hi; r += 256) {
            int2 p = part[r];
            int slot = atomicAdd(&cur[p.y & 255], 1);
            ssrc[slot] = p.x;
        }
        __syncthreads();
        for (int r = t; r < items; r += 256) adj[lo + r] = ssrc[r];
    } else {  // overflow fallback (never for this dataset): unstaged writes
        for (int r = lo + t; r < hi; r += 256) {
            int2 p = part[r];
            int slot = atomicAdd(&cur[p.y & 255], 1);
            adj[lo + slot] = p.x;
        }
    }
}

// ---- w_as = W3 @ a3_src, w_ad = W3 @ a3_dst; and W3 padded to stride 244 ---

__global__ void w3a_kernel(const float* __restrict__ W3,
                           const float* __restrict__ a3s,
                           const float* __restrict__ a3d,
                           float* __restrict__ w_as, float* __restrict__ w_ad) {
    int t = threadIdx.x;  // 128 threads
    if (t >= 128) return;
    int k = t & 63;
    const float* a = (t < 64) ? a3s : a3d;
    float s = 0.f;
    for (int c = 0; c < 242; ++c) s = fmaf(W3[k * 242 + c], a[c], s);
    if (t < 64) w_as[k] = s; else w_ad[k] = s;
}

__global__ __launch_bounds__(256)
void w3pad_kernel(const float* __restrict__ W3, float* __restrict__ W3p) {
    int t = blockIdx.x * blockDim.x + threadIdx.x;  // 64*244
    if (t >= 64 * 244) return;
    int k = t / 244, c = t - k * 244;
    W3p[t] = (c < 242) ? W3[k * 242 + c] : 0.f;
}

// ---------------- GEMM + alpha (layers 1 & 2) — fp16 XW output -------------

template <int K>
__global__ __launch_bounds__(256)
void gemm_alpha_v5(const float* __restrict__ X, const float* __restrict__ W,
                   const float* __restrict__ a_src, const float* __restrict__ a_dst,
                   __half* __restrict__ XWh, float* __restrict__ As, float* __restrict__ Ad,
                   int N) {
    constexpr int S = K + 4;        // padded LDS row stride (floats)
    constexpr int F4R = K / 4;      // float4 per row
    __shared__ float xs[32][S];
    int t = threadIdx.x;
    int block0 = blockIdx.x * 32;

    for (int i = t; i < 32 * F4R; i += 256) {
        int row = i / F4R, c4 = i - row * F4R;
        int node = block0 + row;
        float4 v = (node < N) ? *(const float4*)(X + (size_t)node * K + c4 * 4)
                              : make_float4(0.f, 0.f, 0.f, 0.f);
        *(float4*)(&xs[row][c4 * 4]) = v;
    }
    __syncthreads();

    int wave = t >> 6, lane = t & 63;
    int jj = lane >> 4, cc = lane & 15;
    int r0 = wave * 8 + jj * 2;     // local node pair
    int base = block0 + r0;

    float4 o0 = make_float4(0.f, 0.f, 0.f, 0.f);
    float4 o1 = make_float4(0.f, 0.f, 0.f, 0.f);

    const float* wp = W + cc * 4;
#pragma unroll 2
    for (int k = 0; k < K; k += 4) {
        float4 w0 = *(const float4*)(wp + (size_t)(k + 0) * 64);
        float4 w1 = *(const float4*)(wp + (size_t)(k + 1) * 64);
        float4 w2 = *(const float4*)(wp + (size_t)(k + 2) * 64);
        float4 w3 = *(const float4*)(wp + (size_t)(k + 3) * 64);
        float4 m0 = *(const float4*)(&xs[r0][k]);
        float4 m1 = *(const float4*)(&xs[r0 + 1][k]);

        o0.x = fmaf(m0.x, w0.x, o0.x);
        o0.y = fmaf(m0.x, w0.y, o0.y);
        o0.z = fmaf(m0.x, w0.z, o0.z);
        o0.w = fmaf(m0.x, w0.w, o0.w);
        o0.x = fmaf(m0.y, w1.x, o0.x);
        o0.y = fmaf(m0.y, w1.y, o0.y);
        o0.z = fmaf(m0.y, w1.z, o0.z);
        o0.w = fmaf(m0.y, w1.w, o0.w);
        o0.x = fmaf(m0.z, w2.x, o0.x);
        o0.y = fmaf(m0.z, w2.y, o0.y);
        o0.z = fmaf(m0.z, w2.z, o0.z);
        o0.w = fmaf(m0.z, w2.w, o0.w);
        o0.x = fmaf(m0.w, w3.x, o0.x);
        o0.y = fmaf(m0.w, w3.y, o0.y);
        o0.z = fmaf(m0.w, w3.z, o0.z);
        o0.w = fmaf(m0.w, w3.w, o0.w);

        o1.x = fmaf(m1.x, w0.x, o1.x);
        o1.y = fmaf(m1.x, w0.y, o1.y);
        o1.z = fmaf(m1.x, w0.z, o1.z);
        o1.w = fmaf(m1.x, w0.w, o1.w);
        o1.x = fmaf(m1.y, w1.x, o1.x);
        o1.y = fmaf(m1.y, w1.y, o1.y);
        o1.z = fmaf(m1.y, w1.z, o1.z);
        o1.w = fmaf(m1.y, w1.w, o1.w);
        o1.x = fmaf(m1.z, w2.x, o1.x);
        o1.y = fmaf(m1.z, w2.y, o1.y);
        o1.z = fmaf(m1.z, w2.z, o1.z);
        o1.w = fmaf(m1.z, w2.w, o1.w);
        o1.x = fmaf(m1.w, w3.x, o1.x);
        o1.y = fmaf(m1.w, w3.y, o1.y);
        o1.z = fmaf(m1.w, w3.z, o1.z);
        o1.w = fmaf(m1.w, w3.w, o1.w);
    }

    float4 av = *(const float4*)(a_src + cc * 4);
    float4 dv = *(const float4*)(a_dst + cc * 4);

    if (base < N) {
        union { __half2 h[2]; uint2 u; } pk;
        pk.h[0] = __floats2half2_rn(o0.x, o0.y);
        pk.h[1] = __floats2half2_rn(o0.z, o0.w);
        *(uint2*)(XWh + (size_t)base * 64 + cc * 4) = pk.u;
        float s = o0.x * av.x + o0.y * av.y + o0.z * av.z + o0.w * av.w;
        float d = o0.x * dv.x + o0.y * dv.y + o0.z * dv.z + o0.w * dv.w;
        s += __shfl_xor(s, 1);
        d += __shfl_xor(d, 1);
        if ((cc & 1) == 0) {
            As[base * 8 + (cc >> 1)] = s;
            Ad[base * 8 + (cc >> 1)] = d;
        }
    }
    if (base + 1 < N) {
        union { __half2 h[2]; uint2 u; } pk;
        pk.h[0] = __floats2half2_rn(o1.x, o1.y);
        pk.h[1] = __floats2half2_rn(o1.z, o1.w);
        *(uint2*)(XWh + (size_t)(base + 1) * 64 + cc * 4) = pk.u;
        float s = o1.x * av.x + o1.y * av.y + o1.z * av.z + o1.w * av.w;
        float d = o1.x * dv.x + o1.y * dv.y + o1.z * dv.z + o1.w * dv.w;
        s += __shfl_xor(s, 1);
        d += __shfl_xor(d, 1);
        if ((cc & 1) == 0) {
            As[(base + 1) * 8 + (cc >> 1)] = s;
            Ad[(base + 1) * 8 + (cc >> 1)] = d;
        }
    }
}

// ---------------- Aggregation v4 (layers 1 & 2: H=8, C=8) ------------------
// 16-edge chunks; acc-phase lane = r*32 + c2 loads __half2 (2 channels) of
// edge k+r: one instruction gathers TWO rows. p-phase: two 8-edge sub-phases
// (lane = e*8+h); invalid edges have p=0 so clamped loads contribute 0.
// pk via bpermute from lane ((k&7)+r)*8 + hA, hA = c2>>2. r-halves combined
// with shfl_xor(32); den reduce (xor 8/16/32) unchanged.

template <bool WITH_A3, bool HALF_OUT>
__global__ __launch_bounds__(256)
void agg_h8c8_v4(const __half2* __restrict__ XW, const float* __restrict__ As,
                 const float* __restrict__ Ad, const int* __restrict__ row_ptr,
                 const int* __restrict__ adj, const float* __restrict__ bias,
                 void* __restrict__ OUTv,
                 const float* __restrict__ w_as, const float* __restrict__ w_ad,
                 float* __restrict__ As3, float* __restrict__ Ad3, int N) {
    int wave = threadIdx.x >> 6, lane = threadIdx.x & 63;
    int node = blockIdx.x * 4 + wave;
    if (node >= N) return;
    int beg = row_ptr[node], end = row_ptr[node + 1];
    int eP = lane >> 3, hP = lane & 7;     // p-phase coords
    int r = lane >> 5, c2 = lane & 31;     // acc-phase coords
    int hA = c2 >> 2;                      // head of channels (2c2, 2c2+1)
    float adp = Ad[node * 8 + hP];

    float den_part = 0.f;
    float accx = 0.f, accy = 0.f;
    int idx = beg;
    for (; idx + 16 <= end; idx += 16) {
        int sa = adj[idx + eP];
        int sb = adj[idx + 8 + eP];
        float pa = __expf(lrelu(As[(size_t)sa * 8 + hP] + adp));
        float pb = __expf(lrelu(As[(size_t)sb * 8 + hP] + adp));
        den_part += pa + pb;
        int s[16];
#pragma unroll
        for (int k = 0; k < 16; ++k) s[k] = adj[idx + k];
#pragma unroll
        for (int k = 0; k < 16; k += 2) {
            int row = r ? s[k + 1] : s[k];
            float2 xv = __half22float2(XW[(size_t)row * 32 + c2]);
            float psrc = (k < 8) ? pa : pb;
            float pk = __shfl(psrc, ((k & 7) + r) * 8 + hA);
            accx = fmaf(pk, xv.x, accx);
            accy = fmaf(pk, xv.y, accy);
        }
    }
    int rem = end - idx;
    if (rem > 0) {
        int ca = (eP < rem) ? eP : rem - 1;
        int cb = (8 + eP < rem) ? 8 + eP : rem - 1;
        int sa = adj[idx + ca];
        int sb = adj[idx + cb];
        float pa = (eP < rem) ? __expf(lrelu(As[(size_t)sa * 8 + hP] + adp)) : 0.f;
        float pb = (8 + eP < rem) ? __expf(lrelu(As[(size_t)sb * 8 + hP] + adp)) : 0.f;
        den_part += pa + pb;
        int s[16];
#pragma unroll
        for (int k = 0; k < 16; ++k) s[k] = adj[idx + ((k < rem) ? k : rem - 1)];
#pragma unroll
        for (int k = 0; k < 16; k += 2) {
            if (k >= rem) break;  // wave-uniform
            int row = r ? s[(k + 1 < rem) ? k + 1 : rem - 1] : s[k];
            float2 xv = __half22float2(XW[(size_t)row * 32 + c2]);
            float psrc = (k < 8) ? pa : pb;
            float pk = __shfl(psrc, ((k & 7) + r) * 8 + hA);  // p=0 if edge invalid
            accx = fmaf(pk, xv.x, accx);
            accy = fmaf(pk, xv.y, accy);
        }
    }
    // combine edge-parity halves: lane i and i+32 hold the same channels
    accx += __shfl_xor(accx, 32);
    accy += __shfl_xor(accy, 32);
    // den: sum over e-slots, lane holds den[lane&7]; route den[hA] to acc lane
    den_part += __shfl_xor(den_part, 8);
    den_part += __shfl_xor(den_part, 16);
    den_part += __shfl_xor(den_part, 32);
    float den = __shfl(den_part, hA);

    float rden = 1.f / (den + 1e-16f);
    float vx = fmaxf(accx * rden + bias[c2 * 2], 0.f);
    float vy = fmaxf(accy * rden + bias[c2 * 2 + 1], 0.f);
    if (r == 0) {
        if (HALF_OUT) ((__half2*)OUTv)[(size_t)node * 32 + c2] = __floats2half2_rn(vx, vy);
        else          ((float2*)OUTv)[(size_t)node * 32 + c2] = make_float2(vx, vy);
    }

    if (WITH_A3) {
        // all lanes hold channel sums (lane i == lane i+32); reduce lanes 0..31
        float s3v = vx * w_as[c2 * 2] + vy * w_as[c2 * 2 + 1];
        float d3v = vx * w_ad[c2 * 2] + vy * w_ad[c2 * 2 + 1];
#pragma unroll
        for (int m = 1; m <= 16; m <<= 1) {
            s3v += __shfl_xor(s3v, m);
            d3v += __shfl_xor(d3v, m);
        }
        if (lane == 0) {
            As3[node] = s3v;
            Ad3[node] = d3v;
        }
    }
}

// ---------------- Layer 3 aggregation v4 (H=1, 64 cols) --------------------
// Same half2 gather; p computed 4x-redundantly (lane&15 = edge), den via
// group xor 1/2/4/8; pk broadcast from lane (k+r)&15.

__global__ __launch_bounds__(256)
void agg3msg_v4(const __half2* __restrict__ H2, const float* __restrict__ As3,
                const float* __restrict__ Ad3, const int* __restrict__ row_ptr,
                const int* __restrict__ adj, float* __restrict__ MSG, int N) {
    int wave = threadIdx.x >> 6, lane = threadIdx.x & 63;
    int node = blockIdx.x * 4 + wave;
    if (node >= N) return;
    int beg = row_ptr[node], end = row_ptr[node + 1];
    float ad = Ad3[node];
    int eP = lane & 15;
    int r = lane >> 5, c2 = lane & 31;

    float den_part = 0.f;
    float accx = 0.f, accy = 0.f;
    int idx = beg;
    for (; idx + 16 <= end; idx += 16) {
        int se = adj[idx + eP];
        float p = __expf(lrelu(As3[se] + ad));
        den_part += p;
        int s[16];
#pragma unroll
        for (int k = 0; k < 16; ++k) s[k] = adj[idx + k];
#pragma unroll
        for (int k = 0; k < 16; k += 2) {
            int row = r ? s[k + 1] : s[k];
            float2 xv = __half22float2(H2[(size_t)row * 32 + c2]);
            float pk = __shfl(p, k + r);  // source lanes 0..15 hold p[edge]
            accx = fmaf(pk, xv.x, accx);
            accy = fmaf(pk, xv.y, accy);
        }
    }
    int rem = end - idx;
    if (rem > 0) {
        int ce = (eP < rem) ? eP : rem - 1;
        int se = adj[idx + ce];
        float p = (eP < rem) ? __expf(lrelu(As3[se] + ad)) : 0.f;
        den_part += p;
        int s[16];
#pragma unroll
        for (int k = 0; k < 16; ++k) s[k] = adj[idx + ((k < rem) ? k : rem - 1)];
#pragma unroll
        for (int k = 0; k < 16; k += 2) {
            if (k >= rem) break;  // wave-uniform
            int row = r ? s[(k + 1 < rem) ? k + 1 : rem - 1] : s[k];
            float2 xv = __half22float2(H2[(size_t)row * 32 + c2]);
            float pk = __shfl(p, k + r);  // p=0 if edge invalid
            accx = fmaf(pk, xv.x, accx);
            accy = fmaf(pk, xv.y, accy);
        }
    }
    accx += __shfl_xor(accx, 32);
    accy += __shfl_xor(accy, 32);
    den_part += __shfl_xor(den_part, 1);
    den_part += __shfl_xor(den_part, 2);
    den_part += __shfl_xor(den_part, 4);
    den_part += __shfl_xor(den_part, 8);  // every lane: full den
    float rden = 1.f / (den_part + 1e-16f);
    if (r == 0) {
        ((float2*)MSG)[(size_t)node * 32 + c2] = make_float2(accx * rden, accy * rden);
    }
}

// ---------------- gemm3 v2: OUT = softmax_pairs(relu(MSG @ W3 + b3)) -------

__global__ __launch_bounds__(256)
void gemm3_kernel(const float* __restrict__ MSG, const float* __restrict__ W3p,
                  const float* __restrict__ bias, float* __restrict__ OUT, int N) {
    __shared__ float msh[4][8][64];
    int wave = threadIdx.x >> 6, lane = threadIdx.x & 63;
    int base = blockIdx.x * 32 + wave * 8;

#pragma unroll
    for (int j = 0; j < 8; ++j) {
        int node = base + j;
        msh[wave][j][lane] = (node < N) ? MSG[(size_t)node * 64 + lane] : 0.f;
    }
    // same-wave LDS RAW: DS pipe in-order, compiler inserts lgkmcnt wait

    int c0 = lane * 4;  // lanes 0..60 carry channels; 61-63 idle
    if (c0 < 242) {
        float o[8][4];
#pragma unroll
        for (int j = 0; j < 8; ++j)
#pragma unroll
            for (int q = 0; q < 4; ++q) o[j][q] = 0.f;

#pragma unroll 4
        for (int k = 0; k < 64; k += 4) {
            float4 w0 = *(const float4*)(W3p + (size_t)(k + 0) * 244 + c0);
            float4 w1 = *(const float4*)(W3p + (size_t)(k + 1) * 244 + c0);
            float4 w2 = *(const float4*)(W3p + (size_t)(k + 2) * 244 + c0);
            float4 w3 = *(const float4*)(W3p + (size_t)(k + 3) * 244 + c0);
#pragma unroll
            for (int j = 0; j < 8; ++j) {
                float4 m = *(const float4*)(&msh[wave][j][k]);
                o[j][0] = fmaf(m.x, w0.x, o[j][0]);
                o[j][1] = fmaf(m.x, w0.y, o[j][1]);
                o[j][2] = fmaf(m.x, w0.z, o[j][2]);
                o[j][3] = fmaf(m.x, w0.w, o[j][3]);
                o[j][0] = fmaf(m.y, w1.x, o[j][0]);
                o[j][1] = fmaf(m.y, w1.y, o[j][1]);
                o[j][2] = fmaf(m.y, w1.z, o[j][2]);
                o[j][3] = fmaf(m.y, w1.w, o[j][3]);
                o[j][0] = fmaf(m.z, w2.x, o[j][0]);
                o[j][1] = fmaf(m.z, w2.y, o[j][1]);
                o[j][2] = fmaf(m.z, w2.z, o[j][2]);
                o[j][3] = fmaf(m.z, w2.w, o[j][3]);
                o[j][0] = fmaf(m.w, w3.x, o[j][0]);
                o[j][1] = fmaf(m.w, w3.y, o[j][1]);
                o[j][2] = fmaf(m.w, w3.z, o[j][2]);
                o[j][3] = fmaf(m.w, w3.w, o[j][3]);
            }
        }

        float b0 = bias[c0], b1v = bias[c0 + 1];
        float b2v = (c0 + 2 < 242) ? bias[c0 + 2] : 0.f;
        float b3v = (c0 + 3 < 242) ? bias[c0 + 3] : 0.f;
#pragma unroll
        for (int j = 0; j < 8; ++j) {
            int node = base + j;
            if (node >= N) break;
            size_t out_base = (size_t)node * 242 + c0;
            float v0 = fmaxf(o[j][0] + b0, 0.f);
            float v1 = fmaxf(o[j][1] + b1v, 0.f);
            float m01 = fmaxf(v0, v1);
            float e0 = __expf(v0 - m01), e1 = __expf(v1 - m01);
            float r01 = 1.f / (e0 + e1);
            OUT[out_base]     = e0 * r01;
            OUT[out_base + 1] = e1 * r01;
            if (c0 + 2 < 242) {
                float v2 = fmaxf(o[j][2] + b2v, 0.f);
                float v3 = fmaxf(o[j][3] + b3v, 0.f);
                float m23 = fmaxf(v2, v3);
                float e2 = __expf(v2 - m23), e3 = __expf(v3 - m23);
                float r23 = 1.f / (e2 + e3);
                OUT[out_base + 2] = e2 * r23;
                OUT[out_base + 3] = e3 * r23;
            }
        }
    }
}

// ---------------- launch ----------------

extern "C" void kernel_launch(void* const* d_in, const int* in_sizes, int n_in,
                              void* d_out, int out_size, void* d_ws, size_t ws_size,
                              hipStream_t stream) {
    const float* x   = (const float*)d_in[0];
    const void*  ei  = d_in[1];
    const float* W1  = (const float*)d_in[2];
    const float* a1s = (const float*)d_in[3];
    const float* a1d = (const float*)d_in[4];
    const float* b1  = (const float*)d_in[5];
    const float* W2  = (const float*)d_in[6];
    const float* a2s = (const float*)d_in[7];
    const float* a2d = (const float*)d_in[8];
    const float* b2  = (const float*)d_in[9];
    const float* W3  = (const float*)d_in[10];
    const float* a3s = (const float*)d_in[11];
    const float* a3d = (const float*)d_in[12];
    const float* b3  = (const float*)d_in[13];
    float* out = (float*)d_out;

    const int N = in_sizes[0] / 128;  // 50000
    const int E = in_sizes[1] / 2;    // 800000

    char* w = (char*)d_ws;
    auto alloc = [&](size_t bytes) {
        char* p = w;
        w += (bytes + 255) & ~(size_t)255;
        return p;
    };
    int*   flag    = (int*)alloc(4);
    int*   row_ptr = (int*)alloc(((size_t)N + 1) * 4);
    int*   adj     = (int*)alloc((size_t)(E + N) * 4);
    int*   btot    = (int*)alloc(256 * 4);
    int*   bbase   = (int*)alloc(257 * 4);
    float* As      = (float*)alloc((size_t)N * 8 * 4);
    float* Ad      = (float*)alloc((size_t)N * 8 * 4);
    float* As3     = (float*)alloc((size_t)N * 4);
    float* Ad3     = (float*)alloc((size_t)N * 4);
    float* w_as    = (float*)alloc(64 * 4);
    float* w_ad    = (float*)alloc(64 * 4);
    float* W3p     = (float*)alloc((size_t)64 * 244 * 4);
    float* bufA    = (float*)alloc((size_t)N * 64 * 4);
    float* bufB    = (float*)alloc((size_t)N * 64 * 4);
    // CSR scratch aliased into bufA (12.8MB): part 6.8MB @0, blkhist 256KB @7MB,
    // blkoff 256KB @7.25MB. All dead before gemm1 first writes bufA.
    int2*   part    = (int2*)bufA;
    int*    blkhist = (int*)((char*)bufA + (size_t)7 * 1024 * 1024);
    int*    blkoff  = (int*)((char*)bufA + (size_t)7 * 1024 * 1024 + 256 * 1024);
    // fp16 buffers aliased into bufA (lifetimes disjoint):
    //   XW1h @ bufA[0:6.4e6)        (gemm1 -> agg1)
    //   XW2h @ bufA[6.4e6:12.8e6)   (gemm2 -> agg2)
    //   h2h  @ bufA[0:6.4e6)        (agg2 -> agg3; XW1h dead)
    __half* XW1h = (__half*)bufA;
    __half* XW2h = (__half*)((char*)bufA + (size_t)N * 64 * 2);
    __half* h2h  = (__half*)bufA;
    float*  msg  = bufB;  // h1 dead after gemm2

    int tot  = E + N;                       // 850000
    int nblk = (tot + CH - 1) / CH;         // 208 <= 256
    int nb   = (N + 255) >> 8;              // 196 <= 256

    // CSR build (bucketed counting sort; includes self-loops)
    detect_kernel<<<1, 64, 0, stream>>>((const int*)ei, flag);
    zero_btot_kernel<<<1, 256, 0, stream>>>(btot);
    histA_kernel<<<nblk, 256, 0, stream>>>(ei, flag, blkhist, btot, E, N);
    bucket_scan_kernel<<<1, 256, 0, stream>>>(btot, bbase, nb, tot);
    blk_scan_kernel<<<nb, 256, 0, stream>>>(blkhist, bbase, blkoff, nblk);
    partC_kernel<<<nblk, 256, 0, stream>>>(ei, flag, blkoff, part, E, N);
    csrD_kernel<<<nb, 256, 0, stream>>>(part, bbase, row_ptr, adj, N);
    w3a_kernel<<<1, 128, 0, stream>>>(W3, a3s, a3d, w_as, w_ad);
    w3pad_kernel<<<(64 * 244 + 255) / 256, 256, 0, stream>>>(W3, W3p);

    int nb4 = (N + 3) / 4;
    int nb32 = (N + 31) / 32;

    // Layer 1: x -> XW1h (fp16), agg -> bufB (h1 fp32)
    gemm_alpha_v5<128><<<nb32, 256, 0, stream>>>(x, W1, a1s, a1d, XW1h, As, Ad, N);
    agg_h8c8_v4<false, false><<<nb4, 256, 0, stream>>>((const __half2*)XW1h, As, Ad,
                                                       row_ptr, adj, b1, bufB,
                                                       nullptr, nullptr,
                                                       nullptr, nullptr, N);
    // Layer 2: bufB (fp32) -> XW2h (fp16), agg -> h2h (fp16) + As3/Ad3
    gemm_alpha_v5<64><<<nb32, 256, 0, stream>>>(bufB, W2, a2s, a2d, XW2h, As, Ad, N);
    agg_h8c8_v4<true, true><<<nb4, 256, 0, stream>>>((const __half2*)XW2h, As, Ad,
                                                     row_ptr, adj, b2, h2h,
                                                     w_as, w_ad, As3, Ad3, N);
    // Layer 3: h2h (fp16) -> msg (fp32, bufB), then gemm3 -> out
    agg3msg_v4<<<nb4, 256, 0, stream>>>((const __half2*)h2h, As3, Ad3, row_ptr, adj,
                                        msg, N);
    gemm3_kernel<<<nb32, 256, 0, stream>>>(msg, W3p, b3, out, N);
}

// Round 9
// 363.752 us; speedup vs baseline: 1.2077x; 1.2077x over previous
//
#include <hip/hip_runtime.h>
#include <hip/hip_bf16.h>
#include <hip/hip_fp16.h>

// GAT 3-layer (PPI-style) on MI355X. fp32 tensors; edge_index (2,E) planar,
// int32/int64 via device flag. R17 -> R18:
// R17's half2 gather was poisoned by a private int s[16] with a runtime
// index in the remainder path: AMDGPU promote-alloca put it in LDS
// (LDS_Block_Size 16384, 1.07e7 bank conflicts) -> 73us. R18 keeps the
// half2 two-rows-per-instruction gather but eliminates ALL private arrays:
// every unrolled pair loads its adj entries into named scalars; runtime
// values appear only as address offsets, never as array indices.

#define CH 4096     // items per partition block
#define CAP 8192    // csrD staging capacity (mean bucket = 4352, 60 sigma headroom)

__device__ __forceinline__ float lrelu(float s) { return (s >= 0.f) ? s : 0.2f * s; }

// ---------------- edge dtype detection: (2,E) planar ----------------

__global__ void detect_kernel(const int* __restrict__ ei, int* __restrict__ flag) {
    int t = threadIdx.x;  // 64 lanes
    int v = ei[2 * t + 1];
    unsigned long long b = __ballot(v == 0);
    if (t == 0) *flag = (b == ~0ULL) ? 1 : 0;
}

__device__ __forceinline__ int edge_at(const void* ei, int is64, long long idx) {
    return is64 ? (int)((const long long*)ei)[idx] : ((const int*)ei)[idx];
}

// ---------------- bucketed CSR build ----------------

__global__ void zero_btot_kernel(int* __restrict__ btot) {
    btot[threadIdx.x] = 0;  // 256 threads
}

__global__ __launch_bounds__(256)
void histA_kernel(const void* __restrict__ ei, const int* __restrict__ flag,
                  int* __restrict__ blkhist, int* __restrict__ btot, int E, int N) {
    __shared__ int h[256];
    int t = threadIdx.x;
    h[t] = 0;
    __syncthreads();
    int is64 = *flag;
    long long base = (long long)blockIdx.x * CH;
    long long tot = (long long)E + N;
#pragma unroll
    for (int i = 0; i < CH / 256; ++i) {
        long long idx = base + t + i * 256;
        if (idx < tot) {
            int dst = (idx < E) ? edge_at(ei, is64, (long long)E + idx) : (int)(idx - E);
            atomicAdd(&h[(dst >> 8) & 255], 1);
        }
    }
    __syncthreads();
    int nb = (N + 255) >> 8;
    if (t < nb) {
        blkhist[t * 256 + blockIdx.x] = h[t];
        atomicAdd(&btot[t], h[t]);
    }
}

__global__ __launch_bounds__(256)
void bucket_scan_kernel(const int* __restrict__ btot, int* __restrict__ bbase,
                        int nb, int total) {
    __shared__ int s[256];
    int t = threadIdx.x;
    int v = (t < nb) ? btot[t] : 0;
    s[t] = v;
    __syncthreads();
#pragma unroll
    for (int off = 1; off < 256; off <<= 1) {
        int u = (t >= off) ? s[t - off] : 0;
        __syncthreads();
        s[t] += u;
        __syncthreads();
    }
    if (t < nb) bbase[t] = s[t] - v;
    if (t == 0) bbase[nb] = total;
}

__global__ __launch_bounds__(256)
void blk_scan_kernel(const int* __restrict__ blkhist, const int* __restrict__ bbase,
                     int* __restrict__ blkoff, int nblk) {
    __shared__ int s[256];
    int t = threadIdx.x;
    int b = blockIdx.x;
    int v = (t < nblk) ? blkhist[b * 256 + t] : 0;
    s[t] = v;
    __syncthreads();
#pragma unroll
    for (int off = 1; off < 256; off <<= 1) {
        int u = (t >= off) ? s[t - off] : 0;
        __syncthreads();
        s[t] += u;
        __syncthreads();
    }
    if (t < nblk) blkoff[b * 256 + t] = bbase[b] + s[t] - v;
}

__global__ __launch_bounds__(256)
void partC_kernel(const void* __restrict__ ei, const int* __restrict__ flag,
                  const int* __restrict__ blkoff, int2* __restrict__ part,
                  int E, int N) {
    __shared__ int h[256];
    __shared__ int lst[256];
    __shared__ int cur[256];
    __shared__ int grb[256];
    __shared__ int ssrc[CH];
    __shared__ int sdst[CH];
    int t = threadIdx.x;
    h[t] = 0;
    __syncthreads();
    int is64 = *flag;
    long long base = (long long)blockIdx.x * CH;
    long long tot = (long long)E + N;
    int msrc[CH / 256], mdst[CH / 256], mb[CH / 256];
#pragma unroll
    for (int i = 0; i < CH / 256; ++i) {
        long long idx = base + t + i * 256;
        if (idx < tot) {
            int s, d;
            if (idx < E) {
                s = edge_at(ei, is64, idx);
                d = edge_at(ei, is64, (long long)E + idx);
            } else {
                s = (int)(idx - E);
                d = s;
            }
            msrc[i] = s;
            mdst[i] = d;
            mb[i] = (d >> 8) & 255;
            atomicAdd(&h[mb[i]], 1);
        } else {
            mb[i] = -1;
        }
    }
    __syncthreads();
    int v = h[t];
    lst[t] = v;
    __syncthreads();
#pragma unroll
    for (int off = 1; off < 256; off <<= 1) {
        int u = (t >= off) ? lst[t - off] : 0;
        __syncthreads();
        lst[t] += u;
        __syncthreads();
    }
    int ex = lst[t] - v;
    lst[t] = ex;
    cur[t] = ex;
    int nb = (N + 255) >> 8;
    grb[t] = (t < nb) ? blkoff[t * 256 + blockIdx.x] : 0;
    __syncthreads();
#pragma unroll
    for (int i = 0; i < CH / 256; ++i) {
        if (mb[i] >= 0) {
            int slot = atomicAdd(&cur[mb[i]], 1);
            ssrc[slot] = msrc[i];
            sdst[slot] = mdst[i];
        }
    }
    __syncthreads();
    int items = (int)((tot - base < CH) ? (tot - base) : CH);
    for (int r = t; r < items; r += 256) {
        int d = sdst[r];
        int b = (d >> 8) & 255;
        part[grb[b] + (r - lst[b])] = make_int2(ssrc[r], d);
    }
}

__global__ __launch_bounds__(256)
void csrD_kernel(const int2* __restrict__ part, const int* __restrict__ bbase,
                 int* __restrict__ row_ptr, int* __restrict__ adj, int N) {
    __shared__ int cnt[256];
    __shared__ int lst[256];
    __shared__ int cur[256];
    __shared__ int ssrc[CAP];
    int t = threadIdx.x;
    int b = blockIdx.x;
    int lo = bbase[b], hi = bbase[b + 1];
    int n0 = b << 8;
    cnt[t] = 0;
    __syncthreads();
    for (int r = lo + t; r < hi; r += 256) atomicAdd(&cnt[part[r].y & 255], 1);
    __syncthreads();
    int v = cnt[t];
    lst[t] = v;
    __syncthreads();
#pragma unroll
    for (int off = 1; off < 256; off <<= 1) {
        int u = (t >= off) ? lst[t - off] : 0;
        __syncthreads();
        lst[t] += u;
        __syncthreads();
    }
    int ex = lst[t] - v;
    lst[t] = ex;
    cur[t] = ex;
    __syncthreads();
    if (n0 + t < N) row_ptr[n0 + t] = lo + ex;
    if (b == gridDim.x - 1 && t == 0) row_ptr[N] = hi;
    int items = hi - lo;
    if (items <= CAP) {
        for (int r = lo + t; r < hi; r += 256) {
            int2 p = part[r];
            int slot = atomicAdd(&cur[p.y & 255], 1);
            ssrc[slot] = p.x;
        }
        __syncthreads();
        for (int r = t; r < items; r += 256) adj[lo + r] = ssrc[r];
    } else {  // overflow fallback (never for this dataset): unstaged writes
        for (int r = lo + t; r < hi; r += 256) {
            int2 p = part[r];
            int slot = atomicAdd(&cur[p.y & 255], 1);
            adj[lo + slot] = p.x;
        }
    }
}

// ---- w_as = W3 @ a3_src, w_ad = W3 @ a3_dst; and W3 padded to stride 244 ---

__global__ void w3a_kernel(const float* __restrict__ W3,
                           const float* __restrict__ a3s,
                           const float* __restrict__ a3d,
                           float* __restrict__ w_as, float* __restrict__ w_ad) {
    int t = threadIdx.x;  // 128 threads
    if (t >= 128) return;
    int k = t & 63;
    const float* a = (t < 64) ? a3s : a3d;
    float s = 0.f;
    for (int c = 0; c < 242; ++c) s = fmaf(W3[k * 242 + c], a[c], s);
    if (t < 64) w_as[k] = s; else w_ad[k] = s;
}

__global__ __launch_bounds__(256)
void w3pad_kernel(const float* __restrict__ W3, float* __restrict__ W3p) {
    int t = blockIdx.x * blockDim.x + threadIdx.x;  // 64*244
    if (t >= 64 * 244) return;
    int k = t / 244, c = t - k * 244;
    W3p[t] = (c < 242) ? W3[k * 242 + c] : 0.f;
}

// ---------------- GEMM + alpha (layers 1 & 2) — fp16 XW output -------------

template <int K>
__global__ __launch_bounds__(256)
void gemm_alpha_v5(const float* __restrict__ X, const float* __restrict__ W,
                   const float* __restrict__ a_src, const float* __restrict__ a_dst,
                   __half* __restrict__ XWh, float* __restrict__ As, float* __restrict__ Ad,
                   int N) {
    constexpr int S = K + 4;        // padded LDS row stride (floats)
    constexpr int F4R = K / 4;      // float4 per row
    __shared__ float xs[32][S];
    int t = threadIdx.x;
    int block0 = blockIdx.x * 32;

    for (int i = t; i < 32 * F4R; i += 256) {
        int row = i / F4R, c4 = i - row * F4R;
        int node = block0 + row;
        float4 v = (node < N) ? *(const float4*)(X + (size_t)node * K + c4 * 4)
                              : make_float4(0.f, 0.f, 0.f, 0.f);
        *(float4*)(&xs[row][c4 * 4]) = v;
    }
    __syncthreads();

    int wave = t >> 6, lane = t & 63;
    int jj = lane >> 4, cc = lane & 15;
    int r0 = wave * 8 + jj * 2;     // local node pair
    int base = block0 + r0;

    float4 o0 = make_float4(0.f, 0.f, 0.f, 0.f);
    float4 o1 = make_float4(0.f, 0.f, 0.f, 0.f);

    const float* wp = W + cc * 4;
#pragma unroll 2
    for (int k = 0; k < K; k += 4) {
        float4 w0 = *(const float4*)(wp + (size_t)(k + 0) * 64);
        float4 w1 = *(const float4*)(wp + (size_t)(k + 1) * 64);
        float4 w2 = *(const float4*)(wp + (size_t)(k + 2) * 64);
        float4 w3 = *(const float4*)(wp + (size_t)(k + 3) * 64);
        float4 m0 = *(const float4*)(&xs[r0][k]);
        float4 m1 = *(const float4*)(&xs[r0 + 1][k]);

        o0.x = fmaf(m0.x, w0.x, o0.x);
        o0.y = fmaf(m0.x, w0.y, o0.y);
        o0.z = fmaf(m0.x, w0.z, o0.z);
        o0.w = fmaf(m0.x, w0.w, o0.w);
        o0.x = fmaf(m0.y, w1.x, o0.x);
        o0.y = fmaf(m0.y, w1.y, o0.y);
        o0.z = fmaf(m0.y, w1.z, o0.z);
        o0.w = fmaf(m0.y, w1.w, o0.w);
        o0.x = fmaf(m0.z, w2.x, o0.x);
        o0.y = fmaf(m0.z, w2.y, o0.y);
        o0.z = fmaf(m0.z, w2.z, o0.z);
        o0.w = fmaf(m0.z, w2.w, o0.w);
        o0.x = fmaf(m0.w, w3.x, o0.x);
        o0.y = fmaf(m0.w, w3.y, o0.y);
        o0.z = fmaf(m0.w, w3.z, o0.z);
        o0.w = fmaf(m0.w, w3.w, o0.w);

        o1.x = fmaf(m1.x, w0.x, o1.x);
        o1.y = fmaf(m1.x, w0.y, o1.y);
        o1.z = fmaf(m1.x, w0.z, o1.z);
        o1.w = fmaf(m1.x, w0.w, o1.w);
        o1.x = fmaf(m1.y, w1.x, o1.x);
        o1.y = fmaf(m1.y, w1.y, o1.y);
        o1.z = fmaf(m1.y, w1.z, o1.z);
        o1.w = fmaf(m1.y, w1.w, o1.w);
        o1.x = fmaf(m1.z, w2.x, o1.x);
        o1.y = fmaf(m1.z, w2.y, o1.y);
        o1.z = fmaf(m1.z, w2.z, o1.z);
        o1.w = fmaf(m1.z, w2.w, o1.w);
        o1.x = fmaf(m1.w, w3.x, o1.x);
        o1.y = fmaf(m1.w, w3.y, o1.y);
        o1.z = fmaf(m1.w, w3.z, o1.z);
        o1.w = fmaf(m1.w, w3.w, o1.w);
    }

    float4 av = *(const float4*)(a_src + cc * 4);
    float4 dv = *(const float4*)(a_dst + cc * 4);

    if (base < N) {
        union { __half2 h[2]; uint2 u; } pk;
        pk.h[0] = __floats2half2_rn(o0.x, o0.y);
        pk.h[1] = __floats2half2_rn(o0.z, o0.w);
        *(uint2*)(XWh + (size_t)base * 64 + cc * 4) = pk.u;
        float s = o0.x * av.x + o0.y * av.y + o0.z * av.z + o0.w * av.w;
        float d = o0.x * dv.x + o0.y * dv.y + o0.z * dv.z + o0.w * dv.w;
        s += __shfl_xor(s, 1);
        d += __shfl_xor(d, 1);
        if ((cc & 1) == 0) {
            As[base * 8 + (cc >> 1)] = s;
            Ad[base * 8 + (cc >> 1)] = d;
        }
    }
    if (base + 1 < N) {
        union { __half2 h[2]; uint2 u; } pk;
        pk.h[0] = __floats2half2_rn(o1.x, o1.y);
        pk.h[1] = __floats2half2_rn(o1.z, o1.w);
        *(uint2*)(XWh + (size_t)(base + 1) * 64 + cc * 4) = pk.u;
        float s = o1.x * av.x + o1.y * av.y + o1.z * av.z + o1.w * av.w;
        float d = o1.x * dv.x + o1.y * dv.y + o1.z * dv.z + o1.w * dv.w;
        s += __shfl_xor(s, 1);
        d += __shfl_xor(d, 1);
        if ((cc & 1) == 0) {
            As[(base + 1) * 8 + (cc >> 1)] = s;
            Ad[(base + 1) * 8 + (cc >> 1)] = d;
        }
    }
}

// ---------------- Aggregation v5 (layers 1 & 2: H=8, C=8) ------------------
// 16-edge chunks; acc-phase lane = r*32 + c2 loads __half2 (2 channels) of
// edge k+r: one instruction gathers TWO rows. NO private arrays: each
// unrolled pair loads its adj entries into named scalars (runtime values
// only ever used as address offsets). Invalid edges carry p=0.

#define AGG_PAIR(K_, PSRC_)                                                    \
    {                                                                          \
        int e0_ = adj[idx + (K_)];                                             \
        int e1_ = adj[idx + (K_) + 1];                                         \
        int row_ = r ? e1_ : e0_;                                              \
        float2 xv_ = __half22float2(XW[(size_t)row_ * 32 + c2]);               \
        float pk_ = __shfl((PSRC_), (((K_)&7) + r) * 8 + hA);                  \
        accx = fmaf(pk_, xv_.x, accx);                                         \
        accy = fmaf(pk_, xv_.y, accy);                                         \
    }

#define AGG_PAIR_REM(K_, PSRC_)                                                \
    if ((K_) < rem) {                                                          \
        int e0_ = adj[idx + (K_)];                                             \
        int i1_ = ((K_) + 1 < rem) ? (K_) + 1 : (K_);                          \
        int e1_ = adj[idx + i1_];                                              \
        int row_ = r ? e1_ : e0_;                                              \
        float2 xv_ = __half22float2(XW[(size_t)row_ * 32 + c2]);               \
        float pk_ = __shfl((PSRC_), (((K_)&7) + r) * 8 + hA);                  \
        accx = fmaf(pk_, xv_.x, accx);                                         \
        accy = fmaf(pk_, xv_.y, accy);                                         \
    }

template <bool WITH_A3, bool HALF_OUT>
__global__ __launch_bounds__(256)
void agg_h8c8_v5(const __half2* __restrict__ XW, const float* __restrict__ As,
                 const float* __restrict__ Ad, const int* __restrict__ row_ptr,
                 const int* __restrict__ adj, const float* __restrict__ bias,
                 void* __restrict__ OUTv,
                 const float* __restrict__ w_as, const float* __restrict__ w_ad,
                 float* __restrict__ As3, float* __restrict__ Ad3, int N) {
    int wave = threadIdx.x >> 6, lane = threadIdx.x & 63;
    int node = blockIdx.x * 4 + wave;
    if (node >= N) return;
    int beg = row_ptr[node], end = row_ptr[node + 1];
    int eP = lane >> 3, hP = lane & 7;     // p-phase coords
    int r = lane >> 5, c2 = lane & 31;     // acc-phase coords
    int hA = c2 >> 2;                      // head of channels (2c2, 2c2+1)
    float adp = Ad[node * 8 + hP];

    float den_part = 0.f;
    float accx = 0.f, accy = 0.f;
    int idx = beg;
    for (; idx + 16 <= end; idx += 16) {
        int sa = adj[idx + eP];
        int sb = adj[idx + 8 + eP];
        float pa = __expf(lrelu(As[(size_t)sa * 8 + hP] + adp));
        float pb = __expf(lrelu(As[(size_t)sb * 8 + hP] + adp));
        den_part += pa + pb;
        AGG_PAIR(0, pa)
        AGG_PAIR(2, pa)
        AGG_PAIR(4, pa)
        AGG_PAIR(6, pa)
        AGG_PAIR(8, pb)
        AGG_PAIR(10, pb)
        AGG_PAIR(12, pb)
        AGG_PAIR(14, pb)
    }
    int rem = end - idx;
    if (rem > 0) {
        int ca = (eP < rem) ? eP : rem - 1;
        int cb = (8 + eP < rem) ? 8 + eP : rem - 1;
        int sa = adj[idx + ca];
        int sb = adj[idx + cb];
        float pa = (eP < rem) ? __expf(lrelu(As[(size_t)sa * 8 + hP] + adp)) : 0.f;
        float pb = (8 + eP < rem) ? __expf(lrelu(As[(size_t)sb * 8 + hP] + adp)) : 0.f;
        den_part += pa + pb;
        AGG_PAIR_REM(0, pa)
        AGG_PAIR_REM(2, pa)
        AGG_PAIR_REM(4, pa)
        AGG_PAIR_REM(6, pa)
        AGG_PAIR_REM(8, pb)
        AGG_PAIR_REM(10, pb)
        AGG_PAIR_REM(12, pb)
        AGG_PAIR_REM(14, pb)
    }
    // combine edge-parity halves: lane i and i+32 hold the same channels
    accx += __shfl_xor(accx, 32);
    accy += __shfl_xor(accy, 32);
    // den: sum over e-slots, lane holds den[lane&7]; route den[hA] to acc lane
    den_part += __shfl_xor(den_part, 8);
    den_part += __shfl_xor(den_part, 16);
    den_part += __shfl_xor(den_part, 32);
    float den = __shfl(den_part, hA);

    float rden = 1.f / (den + 1e-16f);
    float vx = fmaxf(accx * rden + bias[c2 * 2], 0.f);
    float vy = fmaxf(accy * rden + bias[c2 * 2 + 1], 0.f);
    if (r == 0) {
        if (HALF_OUT) ((__half2*)OUTv)[(size_t)node * 32 + c2] = __floats2half2_rn(vx, vy);
        else          ((float2*)OUTv)[(size_t)node * 32 + c2] = make_float2(vx, vy);
    }

    if (WITH_A3) {
        // all lanes hold channel sums (lane i == lane i+32); reduce lanes 0..31
        float s3v = vx * w_as[c2 * 2] + vy * w_as[c2 * 2 + 1];
        float d3v = vx * w_ad[c2 * 2] + vy * w_ad[c2 * 2 + 1];
#pragma unroll
        for (int m = 1; m <= 16; m <<= 1) {
            s3v += __shfl_xor(s3v, m);
            d3v += __shfl_xor(d3v, m);
        }
        if (lane == 0) {
            As3[node] = s3v;
            Ad3[node] = d3v;
        }
    }
}

// ---------------- Layer 3 aggregation v5 (H=1, 64 cols) --------------------
// Same half2 gather, array-free; p from lane&15 (4x redundant), den via
// group xor 1/2/4/8; pk broadcast from lane k+r.

#define AGG3_PAIR(K_)                                                          \
    {                                                                          \
        int e0_ = adj[idx + (K_)];                                             \
        int e1_ = adj[idx + (K_) + 1];                                         \
        int row_ = r ? e1_ : e0_;                                              \
        float2 xv_ = __half22float2(H2[(size_t)row_ * 32 + c2]);               \
        float pk_ = __shfl(p, (K_) + r);                                       \
        accx = fmaf(pk_, xv_.x, accx);                                         \
        accy = fmaf(pk_, xv_.y, accy);                                         \
    }

#define AGG3_PAIR_REM(K_)                                                      \
    if ((K_) < rem) {                                                          \
        int e0_ = adj[idx + (K_)];                                             \
        int i1_ = ((K_) + 1 < rem) ? (K_) + 1 : (K_);                          \
        int e1_ = adj[idx + i1_];                                              \
        int row_ = r ? e1_ : e0_;                                              \
        float2 xv_ = __half22float2(H2[(size_t)row_ * 32 + c2]);               \
        float pk_ = __shfl(p, (K_) + r);                                       \
        accx = fmaf(pk_, xv_.x, accx);                                         \
        accy = fmaf(pk_, xv_.y, accy);                                         \
    }

__global__ __launch_bounds__(256)
void agg3msg_v5(const __half2* __restrict__ H2, const float* __restrict__ As3,
                const float* __restrict__ Ad3, const int* __restrict__ row_ptr,
                const int* __restrict__ adj, float* __restrict__ MSG, int N) {
    int wave = threadIdx.x >> 6, lane = threadIdx.x & 63;
    int node = blockIdx.x * 4 + wave;
    if (node >= N) return;
    int beg = row_ptr[node], end = row_ptr[node + 1];
    float ad = Ad3[node];
    int eP = lane & 15;
    int r = lane >> 5, c2 = lane & 31;

    float den_part = 0.f;
    float accx = 0.f, accy = 0.f;
    int idx = beg;
    for (; idx + 16 <= end; idx += 16) {
        int se = adj[idx + eP];
        float p = __expf(lrelu(As3[se] + ad));
        den_part += p;
        AGG3_PAIR(0)
        AGG3_PAIR(2)
        AGG3_PAIR(4)
        AGG3_PAIR(6)
        AGG3_PAIR(8)
        AGG3_PAIR(10)
        AGG3_PAIR(12)
        AGG3_PAIR(14)
    }
    int rem = end - idx;
    if (rem > 0) {
        int ce = (eP < rem) ? eP : rem - 1;
        int se = adj[idx + ce];
        float p = (eP < rem) ? __expf(lrelu(As3[se] + ad)) : 0.f;
        den_part += p;
        AGG3_PAIR_REM(0)
        AGG3_PAIR_REM(2)
        AGG3_PAIR_REM(4)
        AGG3_PAIR_REM(6)
        AGG3_PAIR_REM(8)
        AGG3_PAIR_REM(10)
        AGG3_PAIR_REM(12)
        AGG3_PAIR_REM(14)
    }
    accx += __shfl_xor(accx, 32);
    accy += __shfl_xor(accy, 32);
    den_part += __shfl_xor(den_part, 1);
    den_part += __shfl_xor(den_part, 2);
    den_part += __shfl_xor(den_part, 4);
    den_part += __shfl_xor(den_part, 8);  // every lane: full den
    float rden = 1.f / (den_part + 1e-16f);
    if (r == 0) {
        ((float2*)MSG)[(size_t)node * 32 + c2] = make_float2(accx * rden, accy * rden);
    }
}

// ---------------- gemm3 v2: OUT = softmax_pairs(relu(MSG @ W3 + b3)) -------

__global__ __launch_bounds__(256)
void gemm3_kernel(const float* __restrict__ MSG, const float* __restrict__ W3p,
                  const float* __restrict__ bias, float* __restrict__ OUT, int N) {
    __shared__ float msh[4][8][64];
    int wave = threadIdx.x >> 6, lane = threadIdx.x & 63;
    int base = blockIdx.x * 32 + wave * 8;

#pragma unroll
    for (int j = 0; j < 8; ++j) {
        int node = base + j;
        msh[wave][j][lane] = (node < N) ? MSG[(size_t)node * 64 + lane] : 0.f;
    }
    // same-wave LDS RAW: DS pipe in-order, compiler inserts lgkmcnt wait

    int c0 = lane * 4;  // lanes 0..60 carry channels; 61-63 idle
    if (c0 < 242) {
        float o[8][4];
#pragma unroll
        for (int j = 0; j < 8; ++j)
#pragma unroll
            for (int q = 0; q < 4; ++q) o[j][q] = 0.f;

#pragma unroll 4
        for (int k = 0; k < 64; k += 4) {
            float4 w0 = *(const float4*)(W3p + (size_t)(k + 0) * 244 + c0);
            float4 w1 = *(const float4*)(W3p + (size_t)(k + 1) * 244 + c0);
            float4 w2 = *(const float4*)(W3p + (size_t)(k + 2) * 244 + c0);
            float4 w3 = *(const float4*)(W3p + (size_t)(k + 3) * 244 + c0);
#pragma unroll
            for (int j = 0; j < 8; ++j) {
                float4 m = *(const float4*)(&msh[wave][j][k]);
                o[j][0] = fmaf(m.x, w0.x, o[j][0]);
                o[j][1] = fmaf(m.x, w0.y, o[j][1]);
                o[j][2] = fmaf(m.x, w0.z, o[j][2]);
                o[j][3] = fmaf(m.x, w0.w, o[j][3]);
                o[j][0] = fmaf(m.y, w1.x, o[j][0]);
                o[j][1] = fmaf(m.y, w1.y, o[j][1]);
                o[j][2] = fmaf(m.y, w1.z, o[j][2]);
                o[j][3] = fmaf(m.y, w1.w, o[j][3]);
                o[j][0] = fmaf(m.z, w2.x, o[j][0]);
                o[j][1] = fmaf(m.z, w2.y, o[j][1]);
                o[j][2] = fmaf(m.z, w2.z, o[j][2]);
                o[j][3] = fmaf(m.z, w2.w, o[j][3]);
                o[j][0] = fmaf(m.w, w3.x, o[j][0]);
                o[j][1] = fmaf(m.w, w3.y, o[j][1]);
                o[j][2] = fmaf(m.w, w3.z, o[j][2]);
                o[j][3] = fmaf(m.w, w3.w, o[j][3]);
            }
        }

        float b0 = bias[c0], b1v = bias[c0 + 1];
        float b2v = (c0 + 2 < 242) ? bias[c0 + 2] : 0.f;
        float b3v = (c0 + 3 < 242) ? bias[c0 + 3] : 0.f;
#pragma unroll
        for (int j = 0; j < 8; ++j) {
            int node = base + j;
            if (node >= N) break;
            size_t out_base = (size_t)node * 242 + c0;
            float v0 = fmaxf(o[j][0] + b0, 0.f);
            float v1 = fmaxf(o[j][1] + b1v, 0.f);
            float m01 = fmaxf(v0, v1);
            float e0 = __expf(v0 - m01), e1 = __expf(v1 - m01);
            float r01 = 1.f / (e0 + e1);
            OUT[out_base]     = e0 * r01;
            OUT[out_base + 1] = e1 * r01;
            if (c0 + 2 < 242) {
                float v2 = fmaxf(o[j][2] + b2v, 0.f);
                float v3 = fmaxf(o[j][3] + b3v, 0.f);
                float m23 = fmaxf(v2, v3);
                float e2 = __expf(v2 - m23), e3 = __expf(v3 - m23);
                float r23 = 1.f / (e2 + e3);
                OUT[out_base + 2] = e2 * r23;
                OUT[out_base + 3] = e3 * r23;
            }
        }
    }
}

// ---------------- launch ----------------

extern "C" void kernel_launch(void* const* d_in, const int* in_sizes, int n_in,
                              void* d_out, int out_size, void* d_ws, size_t ws_size,
                              hipStream_t stream) {
    const float* x   = (const float*)d_in[0];
    const void*  ei  = d_in[1];
    const float* W1  = (const float*)d_in[2];
    const float* a1s = (const float*)d_in[3];
    const float* a1d = (const float*)d_in[4];
    const float* b1  = (const float*)d_in[5];
    const float* W2  = (const float*)d_in[6];
    const float* a2s = (const float*)d_in[7];
    const float* a2d = (const float*)d_in[8];
    const float* b2  = (const float*)d_in[9];
    const float* W3  = (const float*)d_in[10];
    const float* a3s = (const float*)d_in[11];
    const float* a3d = (const float*)d_in[12];
    const float* b3  = (const float*)d_in[13];
    float* out = (float*)d_out;

    const int N = in_sizes[0] / 128;  // 50000
    const int E = in_sizes[1] / 2;    // 800000

    char* w = (char*)d_ws;
    auto alloc = [&](size_t bytes) {
        char* p = w;
        w += (bytes + 255) & ~(size_t)255;
        return p;
    };
    int*   flag    = (int*)alloc(4);
    int*   row_ptr = (int*)alloc(((size_t)N + 1) * 4);
    int*   adj     = (int*)alloc((size_t)(E + N) * 4);
    int*   btot    = (int*)alloc(256 * 4);
    int*   bbase   = (int*)alloc(257 * 4);
    float* As      = (float*)alloc((size_t)N * 8 * 4);
    float* Ad      = (float*)alloc((size_t)N * 8 * 4);
    float* As3     = (float*)alloc((size_t)N * 4);
    float* Ad3     = (float*)alloc((size_t)N * 4);
    float* w_as    = (float*)alloc(64 * 4);
    float* w_ad    = (float*)alloc(64 * 4);
    float* W3p     = (float*)alloc((size_t)64 * 244 * 4);
    float* bufA    = (float*)alloc((size_t)N * 64 * 4);
    float* bufB    = (float*)alloc((size_t)N * 64 * 4);
    // CSR scratch aliased into bufA (12.8MB): part 6.8MB @0, blkhist 256KB @7MB,
    // blkoff 256KB @7.25MB. All dead before gemm1 first writes bufA.
    int2*   part    = (int2*)bufA;
    int*    blkhist = (int*)((char*)bufA + (size_t)7 * 1024 * 1024);
    int*    blkoff  = (int*)((char*)bufA + (size_t)7 * 1024 * 1024 + 256 * 1024);
    // fp16 buffers aliased into bufA (lifetimes disjoint):
    //   XW1h @ bufA[0:6.4e6)        (gemm1 -> agg1)
    //   XW2h @ bufA[6.4e6:12.8e6)   (gemm2 -> agg2)
    //   h2h  @ bufA[0:6.4e6)        (agg2 -> agg3; XW1h dead)
    __half* XW1h = (__half*)bufA;
    __half* XW2h = (__half*)((char*)bufA + (size_t)N * 64 * 2);
    __half* h2h  = (__half*)bufA;
    float*  msg  = bufB;  // h1 dead after gemm2

    int tot  = E + N;                       // 850000
    int nblk = (tot + CH - 1) / CH;         // 208 <= 256
    int nb   = (N + 255) >> 8;              // 196 <= 256

    // CSR build (bucketed counting sort; includes self-loops)
    detect_kernel<<<1, 64, 0, stream>>>((const int*)ei, flag);
    zero_btot_kernel<<<1, 256, 0, stream>>>(btot);
    histA_kernel<<<nblk, 256, 0, stream>>>(ei, flag, blkhist, btot, E, N);
    bucket_scan_kernel<<<1, 256, 0, stream>>>(btot, bbase, nb, tot);
    blk_scan_kernel<<<nb, 256, 0, stream>>>(blkhist, bbase, blkoff, nblk);
    partC_kernel<<<nblk, 256, 0, stream>>>(ei, flag, blkoff, part, E, N);
    csrD_kernel<<<nb, 256, 0, stream>>>(part, bbase, row_ptr, adj, N);
    w3a_kernel<<<1, 128, 0, stream>>>(W3, a3s, a3d, w_as, w_ad);
    w3pad_kernel<<<(64 * 244 + 255) / 256, 256, 0, stream>>>(W3, W3p);

    int nb4 = (N + 3) / 4;
    int nb32 = (N + 31) / 32;

    // Layer 1: x -> XW1h (fp16), agg -> bufB (h1 fp32)
    gemm_alpha_v5<128><<<nb32, 256, 0, stream>>>(x, W1, a1s, a1d, XW1h, As, Ad, N);
    agg_h8c8_v5<false, false><<<nb4, 256, 0, stream>>>((const __half2*)XW1h, As, Ad,
                                                       row_ptr, adj, b1, bufB,
                                                       nullptr, nullptr,
                                                       nullptr, nullptr, N);
    // Layer 2: bufB (fp32) -> XW2h (fp16), agg -> h2h (fp16) + As3/Ad3
    gemm_alpha_v5<64><<<nb32, 256, 0, stream>>>(bufB, W2, a2s, a2d, XW2h, As, Ad, N);
    agg_h8c8_v5<true, true><<<nb4, 256, 0, stream>>>((const __half2*)XW2h, As, Ad,
                                                     row_ptr, adj, b2, h2h,
                                                     w_as, w_ad, As3, Ad3, N);
    // Layer 3: h2h (fp16) -> msg (fp32, bufB), then gemm3 -> out
    agg3msg_v5<<<nb4, 256, 0, stream>>>((const __half2*)h2h, As3, Ad3, row_ptr, adj,
                                        msg, N);
    gemm3_kernel<<<nb32, 256, 0, stream>>>(msg, W3p, b3, out, N);
}

// Round 10
// 348.820 us; speedup vs baseline: 1.2594x; 1.0428x over previous
//
#include <hip/hip_runtime.h>
#include <hip/hip_bf16.h>
#include <hip/hip_fp16.h>

// GAT 3-layer (PPI-style) on MI355X. fp32 tensors; edge_index (2,E) planar,
// int32/int64 via device flag. R18 -> R19:
// agg time pinned ~46us across bytes/2, VALU/1.6, instrs/2 -> the binding
// constraint is the per-wave serial chunk chain (adj -> gather -> FMA per
// 16-edge chunk, ~2 dependent round-trips per node at deg~17). v6 pipelines
// 2 chunks in flight via named register sets A/B (clamped loads, p=0 masks
// invalid edges, remainder folded into the pipeline as a partial chunk).
// No private arrays (R17 lesson: runtime-indexed arrays -> LDS promotion).

#define CH 4096     // items per partition block
#define CAP 8192    // csrD staging capacity (mean bucket = 4352, 60 sigma headroom)

__device__ __forceinline__ float lrelu(float s) { return (s >= 0.f) ? s : 0.2f * s; }

// ---------------- edge dtype detection: (2,E) planar ----------------

__global__ void detect_kernel(const int* __restrict__ ei, int* __restrict__ flag) {
    int t = threadIdx.x;  // 64 lanes
    int v = ei[2 * t + 1];
    unsigned long long b = __ballot(v == 0);
    if (t == 0) *flag = (b == ~0ULL) ? 1 : 0;
}

__device__ __forceinline__ int edge_at(const void* ei, int is64, long long idx) {
    return is64 ? (int)((const long long*)ei)[idx] : ((const int*)ei)[idx];
}

// ---------------- bucketed CSR build ----------------

__global__ void zero_btot_kernel(int* __restrict__ btot) {
    btot[threadIdx.x] = 0;  // 256 threads
}

__global__ __launch_bounds__(256)
void histA_kernel(const void* __restrict__ ei, const int* __restrict__ flag,
                  int* __restrict__ blkhist, int* __restrict__ btot, int E, int N) {
    __shared__ int h[256];
    int t = threadIdx.x;
    h[t] = 0;
    __syncthreads();
    int is64 = *flag;
    long long base = (long long)blockIdx.x * CH;
    long long tot = (long long)E + N;
#pragma unroll
    for (int i = 0; i < CH / 256; ++i) {
        long long idx = base + t + i * 256;
        if (idx < tot) {
            int dst = (idx < E) ? edge_at(ei, is64, (long long)E + idx) : (int)(idx - E);
            atomicAdd(&h[(dst >> 8) & 255], 1);
        }
    }
    __syncthreads();
    int nb = (N + 255) >> 8;
    if (t < nb) {
        blkhist[t * 256 + blockIdx.x] = h[t];
        atomicAdd(&btot[t], h[t]);
    }
}

__global__ __launch_bounds__(256)
void bucket_scan_kernel(const int* __restrict__ btot, int* __restrict__ bbase,
                        int nb, int total) {
    __shared__ int s[256];
    int t = threadIdx.x;
    int v = (t < nb) ? btot[t] : 0;
    s[t] = v;
    __syncthreads();
#pragma unroll
    for (int off = 1; off < 256; off <<= 1) {
        int u = (t >= off) ? s[t - off] : 0;
        __syncthreads();
        s[t] += u;
        __syncthreads();
    }
    if (t < nb) bbase[t] = s[t] - v;
    if (t == 0) bbase[nb] = total;
}

__global__ __launch_bounds__(256)
void blk_scan_kernel(const int* __restrict__ blkhist, const int* __restrict__ bbase,
                     int* __restrict__ blkoff, int nblk) {
    __shared__ int s[256];
    int t = threadIdx.x;
    int b = blockIdx.x;
    int v = (t < nblk) ? blkhist[b * 256 + t] : 0;
    s[t] = v;
    __syncthreads();
#pragma unroll
    for (int off = 1; off < 256; off <<= 1) {
        int u = (t >= off) ? s[t - off] : 0;
        __syncthreads();
        s[t] += u;
        __syncthreads();
    }
    if (t < nblk) blkoff[b * 256 + t] = bbase[b] + s[t] - v;
}

__global__ __launch_bounds__(256)
void partC_kernel(const void* __restrict__ ei, const int* __restrict__ flag,
                  const int* __restrict__ blkoff, int2* __restrict__ part,
                  int E, int N) {
    __shared__ int h[256];
    __shared__ int lst[256];
    __shared__ int cur[256];
    __shared__ int grb[256];
    __shared__ int ssrc[CH];
    __shared__ int sdst[CH];
    int t = threadIdx.x;
    h[t] = 0;
    __syncthreads();
    int is64 = *flag;
    long long base = (long long)blockIdx.x * CH;
    long long tot = (long long)E + N;
    int msrc[CH / 256], mdst[CH / 256], mb[CH / 256];
#pragma unroll
    for (int i = 0; i < CH / 256; ++i) {
        long long idx = base + t + i * 256;
        if (idx < tot) {
            int s, d;
            if (idx < E) {
                s = edge_at(ei, is64, idx);
                d = edge_at(ei, is64, (long long)E + idx);
            } else {
                s = (int)(idx - E);
                d = s;
            }
            msrc[i] = s;
            mdst[i] = d;
            mb[i] = (d >> 8) & 255;
            atomicAdd(&h[mb[i]], 1);
        } else {
            mb[i] = -1;
        }
    }
    __syncthreads();
    int v = h[t];
    lst[t] = v;
    __syncthreads();
#pragma unroll
    for (int off = 1; off < 256; off <<= 1) {
        int u = (t >= off) ? lst[t - off] : 0;
        __syncthreads();
        lst[t] += u;
        __syncthreads();
    }
    int ex = lst[t] - v;
    lst[t] = ex;
    cur[t] = ex;
    int nb = (N + 255) >> 8;
    grb[t] = (t < nb) ? blkoff[t * 256 + blockIdx.x] : 0;
    __syncthreads();
#pragma unroll
    for (int i = 0; i < CH / 256; ++i) {
        if (mb[i] >= 0) {
            int slot = atomicAdd(&cur[mb[i]], 1);
            ssrc[slot] = msrc[i];
            sdst[slot] = mdst[i];
        }
    }
    __syncthreads();
    int items = (int)((tot - base < CH) ? (tot - base) : CH);
    for (int r = t; r < items; r += 256) {
        int d = sdst[r];
        int b = (d >> 8) & 255;
        part[grb[b] + (r - lst[b])] = make_int2(ssrc[r], d);
    }
}

__global__ __launch_bounds__(256)
void csrD_kernel(const int2* __restrict__ part, const int* __restrict__ bbase,
                 int* __restrict__ row_ptr, int* __restrict__ adj, int N) {
    __shared__ int cnt[256];
    __shared__ int lst[256];
    __shared__ int cur[256];
    __shared__ int ssrc[CAP];
    int t = threadIdx.x;
    int b = blockIdx.x;
    int lo = bbase[b], hi = bbase[b + 1];
    int n0 = b << 8;
    cnt[t] = 0;
    __syncthreads();
    for (int r = lo + t; r < hi; r += 256) atomicAdd(&cnt[part[r].y & 255], 1);
    __syncthreads();
    int v = cnt[t];
    lst[t] = v;
    __syncthreads();
#pragma unroll
    for (int off = 1; off < 256; off <<= 1) {
        int u = (t >= off) ? lst[t - off] : 0;
        __syncthreads();
        lst[t] += u;
        __syncthreads();
    }
    int ex = lst[t] - v;
    lst[t] = ex;
    cur[t] = ex;
    __syncthreads();
    if (n0 + t < N) row_ptr[n0 + t] = lo + ex;
    if (b == gridDim.x - 1 && t == 0) row_ptr[N] = hi;
    int items = hi - lo;
    if (items <= CAP) {
        for (int r = lo + t; r < hi; r += 256) {
            int2 p = part[r];
            int slot = atomicAdd(&cur[p.y & 255], 1);
            ssrc[slot] = p.x;
        }
        __syncthreads();
        for (int r = t; r < items; r += 256) adj[lo + r] = ssrc[r];
    } else {  // overflow fallback (never for this dataset): unstaged writes
        for (int r = lo + t; r < hi; r += 256) {
            int2 p = part[r];
            int slot = atomicAdd(&cur[p.y & 255], 1);
            adj[lo + slot] = p.x;
        }
    }
}

// ---- w_as = W3 @ a3_src, w_ad = W3 @ a3_dst; and W3 padded to stride 244 ---

__global__ void w3a_kernel(const float* __restrict__ W3,
                           const float* __restrict__ a3s,
                           const float* __restrict__ a3d,
                           float* __restrict__ w_as, float* __restrict__ w_ad) {
    int t = threadIdx.x;  // 128 threads
    if (t >= 128) return;
    int k = t & 63;
    const float* a = (t < 64) ? a3s : a3d;
    float s = 0.f;
    for (int c = 0; c < 242; ++c) s = fmaf(W3[k * 242 + c], a[c], s);
    if (t < 64) w_as[k] = s; else w_ad[k] = s;
}

__global__ __launch_bounds__(256)
void w3pad_kernel(const float* __restrict__ W3, float* __restrict__ W3p) {
    int t = blockIdx.x * blockDim.x + threadIdx.x;  // 64*244
    if (t >= 64 * 244) return;
    int k = t / 244, c = t - k * 244;
    W3p[t] = (c < 242) ? W3[k * 242 + c] : 0.f;
}

// ---------------- GEMM + alpha (layers 1 & 2) — fp16 XW output -------------

template <int K>
__global__ __launch_bounds__(256)
void gemm_alpha_v5(const float* __restrict__ X, const float* __restrict__ W,
                   const float* __restrict__ a_src, const float* __restrict__ a_dst,
                   __half* __restrict__ XWh, float* __restrict__ As, float* __restrict__ Ad,
                   int N) {
    constexpr int S = K + 4;        // padded LDS row stride (floats)
    constexpr int F4R = K / 4;      // float4 per row
    __shared__ float xs[32][S];
    int t = threadIdx.x;
    int block0 = blockIdx.x * 32;

    for (int i = t; i < 32 * F4R; i += 256) {
        int row = i / F4R, c4 = i - row * F4R;
        int node = block0 + row;
        float4 v = (node < N) ? *(const float4*)(X + (size_t)node * K + c4 * 4)
                              : make_float4(0.f, 0.f, 0.f, 0.f);
        *(float4*)(&xs[row][c4 * 4]) = v;
    }
    __syncthreads();

    int wave = t >> 6, lane = t & 63;
    int jj = lane >> 4, cc = lane & 15;
    int r0 = wave * 8 + jj * 2;     // local node pair
    int base = block0 + r0;

    float4 o0 = make_float4(0.f, 0.f, 0.f, 0.f);
    float4 o1 = make_float4(0.f, 0.f, 0.f, 0.f);

    const float* wp = W + cc * 4;
#pragma unroll 2
    for (int k = 0; k < K; k += 4) {
        float4 w0 = *(const float4*)(wp + (size_t)(k + 0) * 64);
        float4 w1 = *(const float4*)(wp + (size_t)(k + 1) * 64);
        float4 w2 = *(const float4*)(wp + (size_t)(k + 2) * 64);
        float4 w3 = *(const float4*)(wp + (size_t)(k + 3) * 64);
        float4 m0 = *(const float4*)(&xs[r0][k]);
        float4 m1 = *(const float4*)(&xs[r0 + 1][k]);

        o0.x = fmaf(m0.x, w0.x, o0.x);
        o0.y = fmaf(m0.x, w0.y, o0.y);
        o0.z = fmaf(m0.x, w0.z, o0.z);
        o0.w = fmaf(m0.x, w0.w, o0.w);
        o0.x = fmaf(m0.y, w1.x, o0.x);
        o0.y = fmaf(m0.y, w1.y, o0.y);
        o0.z = fmaf(m0.y, w1.z, o0.z);
        o0.w = fmaf(m0.y, w1.w, o0.w);
        o0.x = fmaf(m0.z, w2.x, o0.x);
        o0.y = fmaf(m0.z, w2.y, o0.y);
        o0.z = fmaf(m0.z, w2.z, o0.z);
        o0.w = fmaf(m0.z, w2.w, o0.w);
        o0.x = fmaf(m0.w, w3.x, o0.x);
        o0.y = fmaf(m0.w, w3.y, o0.y);
        o0.z = fmaf(m0.w, w3.z, o0.z);
        o0.w = fmaf(m0.w, w3.w, o0.w);

        o1.x = fmaf(m1.x, w0.x, o1.x);
        o1.y = fmaf(m1.x, w0.y, o1.y);
        o1.z = fmaf(m1.x, w0.z, o1.z);
        o1.w = fmaf(m1.x, w0.w, o1.w);
        o1.x = fmaf(m1.y, w1.x, o1.x);
        o1.y = fmaf(m1.y, w1.y, o1.y);
        o1.z = fmaf(m1.y, w1.z, o1.z);
        o1.w = fmaf(m1.y, w1.w, o1.w);
        o1.x = fmaf(m1.z, w2.x, o1.x);
        o1.y = fmaf(m1.z, w2.y, o1.y);
        o1.z = fmaf(m1.z, w2.z, o1.z);
        o1.w = fmaf(m1.z, w2.w, o1.w);
        o1.x = fmaf(m1.w, w3.x, o1.x);
        o1.y = fmaf(m1.w, w3.y, o1.y);
        o1.z = fmaf(m1.w, w3.z, o1.z);
        o1.w = fmaf(m1.w, w3.w, o1.w);
    }

    float4 av = *(const float4*)(a_src + cc * 4);
    float4 dv = *(const float4*)(a_dst + cc * 4);

    if (base < N) {
        union { __half2 h[2]; uint2 u; } pk;
        pk.h[0] = __floats2half2_rn(o0.x, o0.y);
        pk.h[1] = __floats2half2_rn(o0.z, o0.w);
        *(uint2*)(XWh + (size_t)base * 64 + cc * 4) = pk.u;
        float s = o0.x * av.x + o0.y * av.y + o0.z * av.z + o0.w * av.w;
        float d = o0.x * dv.x + o0.y * dv.y + o0.z * dv.z + o0.w * dv.w;
        s += __shfl_xor(s, 1);
        d += __shfl_xor(d, 1);
        if ((cc & 1) == 0) {
            As[base * 8 + (cc >> 1)] = s;
            Ad[base * 8 + (cc >> 1)] = d;
        }
    }
    if (base + 1 < N) {
        union { __half2 h[2]; uint2 u; } pk;
        pk.h[0] = __floats2half2_rn(o1.x, o1.y);
        pk.h[1] = __floats2half2_rn(o1.z, o1.w);
        *(uint2*)(XWh + (size_t)(base + 1) * 64 + cc * 4) = pk.u;
        float s = o1.x * av.x + o1.y * av.y + o1.z * av.z + o1.w * av.w;
        float d = o1.x * dv.x + o1.y * dv.y + o1.z * dv.z + o1.w * dv.w;
        s += __shfl_xor(s, 1);
        d += __shfl_xor(d, 1);
        if ((cc & 1) == 0) {
            As[(base + 1) * 8 + (cc >> 1)] = s;
            Ad[(base + 1) * 8 + (cc >> 1)] = d;
        }
    }
}

// ---------------- Aggregation v6 (layers 1 & 2: H=8, C=8) ------------------
// 2-deep software pipeline over clamped 16-edge chunks (register sets A/B):
// ISSUE loads adj (clamped to end-1) and fires 8 half2-row gathers + 2 As
// gathers into named regs; CONSUME computes masked p (0 for clamped edges),
// shuffles, FMAs. Two chunks' ~20 gathers stay in flight -> 2x per-wave MLP.
// No private arrays (R17 lesson).

#define AISSUE(S, KK)                                                          \
    {                                                                          \
        int b_ = beg + ((KK) << 4);                                            \
        int lim_ = end - 1;                                                    \
        int ia_ = b_ + eP; ia_ = (ia_ < lim_) ? ia_ : lim_;                    \
        int ib_ = b_ + 8 + eP; ib_ = (ib_ < lim_) ? ib_ : lim_;                \
        int sa_ = adj[ia_];                                                    \
        int sb_ = adj[ib_];                                                    \
        asa##S = As[(size_t)sa_ * 8 + hP];                                     \
        asb##S = As[(size_t)sb_ * 8 + hP];                                     \
        ALD(S, 0, b_, lim_) ALD(S, 1, b_, lim_) ALD(S, 2, b_, lim_)            \
        ALD(S, 3, b_, lim_) ALD(S, 4, b_, lim_) ALD(S, 5, b_, lim_)            \
        ALD(S, 6, b_, lim_) ALD(S, 7, b_, lim_)                                \
    }

#define ALD(S, J, B, LIM)                                                      \
    {                                                                          \
        int i0_ = (B) + 2 * (J); i0_ = (i0_ < (LIM)) ? i0_ : (LIM);            \
        int i1_ = (B) + 2 * (J) + 1; i1_ = (i1_ < (LIM)) ? i1_ : (LIM);        \
        int e0_ = adj[i0_];                                                    \
        int e1_ = adj[i1_];                                                    \
        int row_ = r ? e1_ : e0_;                                              \
        g##S##J = XW[(size_t)row_ * 32 + c2];                                  \
    }

#define ACONS(S, KK)                                                           \
    {                                                                          \
        int b_ = beg + ((KK) << 4);                                            \
        float pa_ = (b_ + eP < end) ? __expf(lrelu(asa##S + adp)) : 0.f;       \
        float pb_ = (b_ + 8 + eP < end) ? __expf(lrelu(asb##S + adp)) : 0.f;   \
        den_part += pa_ + pb_;                                                 \
        APC(S, 0, pa_) APC(S, 1, pa_) APC(S, 2, pa_) APC(S, 3, pa_)            \
        APC(S, 4, pb_) APC(S, 5, pb_) APC(S, 6, pb_) APC(S, 7, pb_)            \
    }

#define APC(S, J, P)                                                           \
    {                                                                          \
        float2 xv_ = __half22float2(g##S##J);                                  \
        float pk_ = __shfl((P), (((2 * (J)) & 7) + r) * 8 + hA);               \
        accx = fmaf(pk_, xv_.x, accx);                                         \
        accy = fmaf(pk_, xv_.y, accy);                                         \
    }

template <bool WITH_A3, bool HALF_OUT>
__global__ __launch_bounds__(256)
void agg_h8c8_v6(const __half2* __restrict__ XW, const float* __restrict__ As,
                 const float* __restrict__ Ad, const int* __restrict__ row_ptr,
                 const int* __restrict__ adj, const float* __restrict__ bias,
                 void* __restrict__ OUTv,
                 const float* __restrict__ w_as, const float* __restrict__ w_ad,
                 float* __restrict__ As3, float* __restrict__ Ad3, int N) {
    int wave = threadIdx.x >> 6, lane = threadIdx.x & 63;
    int node = blockIdx.x * 4 + wave;
    if (node >= N) return;
    int beg = row_ptr[node], end = row_ptr[node + 1];
    int eP = lane >> 3, hP = lane & 7;     // p-phase coords
    int r = lane >> 5, c2 = lane & 31;     // acc-phase coords
    int hA = c2 >> 2;                      // head of channels (2c2, 2c2+1)
    float adp = Ad[node * 8 + hP];

    float den_part = 0.f;
    float accx = 0.f, accy = 0.f;
    float asaA, asbA, asaB, asbB;
    __half2 gA0, gA1, gA2, gA3, gA4, gA5, gA6, gA7;
    __half2 gB0, gB1, gB2, gB3, gB4, gB5, gB6, gB7;

    int T = (end - beg + 15) >> 4;   // >= 1 (self-loops guarantee deg >= 1)
    AISSUE(A, 0)
    int k = 0;
    while (k + 2 < T) {
        AISSUE(B, k + 1)
        ACONS(A, k)
        AISSUE(A, k + 2)
        ACONS(B, k + 1)
        k += 2;
    }
    if (k + 1 < T) {
        AISSUE(B, k + 1)
        ACONS(A, k)
        ACONS(B, k + 1)
    } else {
        ACONS(A, k)
    }

    // combine edge-parity halves: lane i and i+32 hold the same channels
    accx += __shfl_xor(accx, 32);
    accy += __shfl_xor(accy, 32);
    // den: sum over e-slots, lane holds den[lane&7]; route den[hA] to acc lane
    den_part += __shfl_xor(den_part, 8);
    den_part += __shfl_xor(den_part, 16);
    den_part += __shfl_xor(den_part, 32);
    float den = __shfl(den_part, hA);

    float rden = 1.f / (den + 1e-16f);
    float vx = fmaxf(accx * rden + bias[c2 * 2], 0.f);
    float vy = fmaxf(accy * rden + bias[c2 * 2 + 1], 0.f);
    if (r == 0) {
        if (HALF_OUT) ((__half2*)OUTv)[(size_t)node * 32 + c2] = __floats2half2_rn(vx, vy);
        else          ((float2*)OUTv)[(size_t)node * 32 + c2] = make_float2(vx, vy);
    }

    if (WITH_A3) {
        // all lanes hold channel sums (lane i == lane i+32); reduce lanes 0..31
        float s3v = vx * w_as[c2 * 2] + vy * w_as[c2 * 2 + 1];
        float d3v = vx * w_ad[c2 * 2] + vy * w_ad[c2 * 2 + 1];
#pragma unroll
        for (int m = 1; m <= 16; m <<= 1) {
            s3v += __shfl_xor(s3v, m);
            d3v += __shfl_xor(d3v, m);
        }
        if (lane == 0) {
            As3[node] = s3v;
            Ad3[node] = d3v;
        }
    }
}

// ---------------- Layer 3 aggregation v6 (H=1, 64 cols) --------------------
// Same 2-deep pipeline; p computed on all lanes (e = lane&15, 4x redundant),
// den via group xor 1/2/4/8; pk broadcast from lane 2J+r.

#define BISSUE(S, KK)                                                          \
    {                                                                          \
        int b_ = beg + ((KK) << 4);                                            \
        int lim_ = end - 1;                                                    \
        int ie_ = b_ + eP3; ie_ = (ie_ < lim_) ? ie_ : lim_;                   \
        int se_ = adj[ie_];                                                    \
        as3##S = As3[se_];                                                     \
        BLD(S, 0, b_, lim_) BLD(S, 1, b_, lim_) BLD(S, 2, b_, lim_)            \
        BLD(S, 3, b_, lim_) BLD(S, 4, b_, lim_) BLD(S, 5, b_, lim_)            \
        BLD(S, 6, b_, lim_) BLD(S, 7, b_, lim_)                                \
    }

#define BLD(S, J, B, LIM)                                                      \
    {                                                                          \
        int i0_ = (B) + 2 * (J); i0_ = (i0_ < (LIM)) ? i0_ : (LIM);            \
        int i1_ = (B) + 2 * (J) + 1; i1_ = (i1_ < (LIM)) ? i1_ : (LIM);        \
        int e0_ = adj[i0_];                                                    \
        int e1_ = adj[i1_];                                                    \
        int row_ = r ? e1_ : e0_;                                              \
        q##S##J = H2[(size_t)row_ * 32 + c2];                                  \
    }

#define BCONS(S, KK)                                                           \
    {                                                                          \
        int b_ = beg + ((KK) << 4);                                            \
        float p_ = (b_ + eP3 < end) ? __expf(lrelu(as3##S + ad)) : 0.f;        \
        den_part += p_;                                                        \
        BPC(S, 0, p_) BPC(S, 1, p_) BPC(S, 2, p_) BPC(S, 3, p_)                \
        BPC(S, 4, p_) BPC(S, 5, p_) BPC(S, 6, p_) BPC(S, 7, p_)                \
    }

#define BPC(S, J, P)                                                           \
    {                                                                          \
        float2 xv_ = __half22float2(q##S##J);                                  \
        float pk_ = __shfl((P), 2 * (J) + r);                                  \
        accx = fmaf(pk_, xv_.x, accx);                                         \
        accy = fmaf(pk_, xv_.y, accy);                                         \
    }

__global__ __launch_bounds__(256)
void agg3msg_v6(const __half2* __restrict__ H2, const float* __restrict__ As3,
                const float* __restrict__ Ad3, const int* __restrict__ row_ptr,
                const int* __restrict__ adj, float* __restrict__ MSG, int N) {
    int wave = threadIdx.x >> 6, lane = threadIdx.x & 63;
    int node = blockIdx.x * 4 + wave;
    if (node >= N) return;
    int beg = row_ptr[node], end = row_ptr[node + 1];
    float ad = Ad3[node];
    int eP3 = lane & 15;
    int r = lane >> 5, c2 = lane & 31;

    float den_part = 0.f;
    float accx = 0.f, accy = 0.f;
    float as3A, as3B;
    __half2 qA0, qA1, qA2, qA3, qA4, qA5, qA6, qA7;
    __half2 qB0, qB1, qB2, qB3, qB4, qB5, qB6, qB7;

    int T = (end - beg + 15) >> 4;
    BISSUE(A, 0)
    int k = 0;
    while (k + 2 < T) {
        BISSUE(B, k + 1)
        BCONS(A, k)
        BISSUE(A, k + 2)
        BCONS(B, k + 1)
        k += 2;
    }
    if (k + 1 < T) {
        BISSUE(B, k + 1)
        BCONS(A, k)
        BCONS(B, k + 1)
    } else {
        BCONS(A, k)
    }

    accx += __shfl_xor(accx, 32);
    accy += __shfl_xor(accy, 32);
    den_part += __shfl_xor(den_part, 1);
    den_part += __shfl_xor(den_part, 2);
    den_part += __shfl_xor(den_part, 4);
    den_part += __shfl_xor(den_part, 8);  // every lane: full den
    float rden = 1.f / (den_part + 1e-16f);
    if (r == 0) {
        ((float2*)MSG)[(size_t)node * 32 + c2] = make_float2(accx * rden, accy * rden);
    }
}

// ---------------- gemm3 v2: OUT = softmax_pairs(relu(MSG @ W3 + b3)) -------

__global__ __launch_bounds__(256)
void gemm3_kernel(const float* __restrict__ MSG, const float* __restrict__ W3p,
                  const float* __restrict__ bias, float* __restrict__ OUT, int N) {
    __shared__ float msh[4][8][64];
    int wave = threadIdx.x >> 6, lane = threadIdx.x & 63;
    int base = blockIdx.x * 32 + wave * 8;

#pragma unroll
    for (int j = 0; j < 8; ++j) {
        int node = base + j;
        msh[wave][j][lane] = (node < N) ? MSG[(size_t)node * 64 + lane] : 0.f;
    }
    // same-wave LDS RAW: DS pipe in-order, compiler inserts lgkmcnt wait

    int c0 = lane * 4;  // lanes 0..60 carry channels; 61-63 idle
    if (c0 < 242) {
        float o[8][4];
#pragma unroll
        for (int j = 0; j < 8; ++j)
#pragma unroll
            for (int q = 0; q < 4; ++q) o[j][q] = 0.f;

#pragma unroll 4
        for (int k = 0; k < 64; k += 4) {
            float4 w0 = *(const float4*)(W3p + (size_t)(k + 0) * 244 + c0);
            float4 w1 = *(const float4*)(W3p + (size_t)(k + 1) * 244 + c0);
            float4 w2 = *(const float4*)(W3p + (size_t)(k + 2) * 244 + c0);
            float4 w3 = *(const float4*)(W3p + (size_t)(k + 3) * 244 + c0);
#pragma unroll
            for (int j = 0; j < 8; ++j) {
                float4 m = *(const float4*)(&msh[wave][j][k]);
                o[j][0] = fmaf(m.x, w0.x, o[j][0]);
                o[j][1] = fmaf(m.x, w0.y, o[j][1]);
                o[j][2] = fmaf(m.x, w0.z, o[j][2]);
                o[j][3] = fmaf(m.x, w0.w, o[j][3]);
                o[j][0] = fmaf(m.y, w1.x, o[j][0]);
                o[j][1] = fmaf(m.y, w1.y, o[j][1]);
                o[j][2] = fmaf(m.y, w1.z, o[j][2]);
                o[j][3] = fmaf(m.y, w1.w, o[j][3]);
                o[j][0] = fmaf(m.z, w2.x, o[j][0]);
                o[j][1] = fmaf(m.z, w2.y, o[j][1]);
                o[j][2] = fmaf(m.z, w2.z, o[j][2]);
                o[j][3] = fmaf(m.z, w2.w, o[j][3]);
                o[j][0] = fmaf(m.w, w3.x, o[j][0]);
                o[j][1] = fmaf(m.w, w3.y, o[j][1]);
                o[j][2] = fmaf(m.w, w3.z, o[j][2]);
                o[j][3] = fmaf(m.w, w3.w, o[j][3]);
            }
        }

        float b0 = bias[c0], b1v = bias[c0 + 1];
        float b2v = (c0 + 2 < 242) ? bias[c0 + 2] : 0.f;
        float b3v = (c0 + 3 < 242) ? bias[c0 + 3] : 0.f;
#pragma unroll
        for (int j = 0; j < 8; ++j) {
            int node = base + j;
            if (node >= N) break;
            size_t out_base = (size_t)node * 242 + c0;
            float v0 = fmaxf(o[j][0] + b0, 0.f);
            float v1 = fmaxf(o[j][1] + b1v, 0.f);
            float m01 = fmaxf(v0, v1);
            float e0 = __expf(v0 - m01), e1 = __expf(v1 - m01);
            float r01 = 1.f / (e0 + e1);
            OUT[out_base]     = e0 * r01;
            OUT[out_base + 1] = e1 * r01;
            if (c0 + 2 < 242) {
                float v2 = fmaxf(o[j][2] + b2v, 0.f);
                float v3 = fmaxf(o[j][3] + b3v, 0.f);
                float m23 = fmaxf(v2, v3);
                float e2 = __expf(v2 - m23), e3 = __expf(v3 - m23);
                float r23 = 1.f / (e2 + e3);
                OUT[out_base + 2] = e2 * r23;
                OUT[out_base + 3] = e3 * r23;
            }
        }
    }
}

// ---------------- launch ----------------

extern "C" void kernel_launch(void* const* d_in, const int* in_sizes, int n_in,
                              void* d_out, int out_size, void* d_ws, size_t ws_size,
                              hipStream_t stream) {
    const float* x   = (const float*)d_in[0];
    const void*  ei  = d_in[1];
    const float* W1  = (const float*)d_in[2];
    const float* a1s = (const float*)d_in[3];
    const float* a1d = (const float*)d_in[4];
    const float* b1  = (const float*)d_in[5];
    const float* W2  = (const float*)d_in[6];
    const float* a2s = (const float*)d_in[7];
    const float* a2d = (const float*)d_in[8];
    const float* b2  = (const float*)d_in[9];
    const float* W3  = (const float*)d_in[10];
    const float* a3s = (const float*)d_in[11];
    const float* a3d = (const float*)d_in[12];
    const float* b3  = (const float*)d_in[13];
    float* out = (float*)d_out;

    const int N = in_sizes[0] / 128;  // 50000
    const int E = in_sizes[1] / 2;    // 800000

    char* w = (char*)d_ws;
    auto alloc = [&](size_t bytes) {
        char* p = w;
        w += (bytes + 255) & ~(size_t)255;
        return p;
    };
    int*   flag    = (int*)alloc(4);
    int*   row_ptr = (int*)alloc(((size_t)N + 1) * 4);
    int*   adj     = (int*)alloc((size_t)(E + N) * 4);
    int*   btot    = (int*)alloc(256 * 4);
    int*   bbase   = (int*)alloc(257 * 4);
    float* As      = (float*)alloc((size_t)N * 8 * 4);
    float* Ad      = (float*)alloc((size_t)N * 8 * 4);
    float* As3     = (float*)alloc((size_t)N * 4);
    float* Ad3     = (float*)alloc((size_t)N * 4);
    float* w_as    = (float*)alloc(64 * 4);
    float* w_ad    = (float*)alloc(64 * 4);
    float* W3p     = (float*)alloc((size_t)64 * 244 * 4);
    float* bufA    = (float*)alloc((size_t)N * 64 * 4);
    float* bufB    = (float*)alloc((size_t)N * 64 * 4);
    // CSR scratch aliased into bufA (12.8MB): part 6.8MB @0, blkhist 256KB @7MB,
    // blkoff 256KB @7.25MB. All dead before gemm1 first writes bufA.
    int2*   part    = (int2*)bufA;
    int*    blkhist = (int*)((char*)bufA + (size_t)7 * 1024 * 1024);
    int*    blkoff  = (int*)((char*)bufA + (size_t)7 * 1024 * 1024 + 256 * 1024);
    // fp16 buffers aliased into bufA (lifetimes disjoint):
    //   XW1h @ bufA[0:6.4e6)        (gemm1 -> agg1)
    //   XW2h @ bufA[6.4e6:12.8e6)   (gemm2 -> agg2)
    //   h2h  @ bufA[0:6.4e6)        (agg2 -> agg3; XW1h dead)
    __half* XW1h = (__half*)bufA;
    __half* XW2h = (__half*)((char*)bufA + (size_t)N * 64 * 2);
    __half* h2h  = (__half*)bufA;
    float*  msg  = bufB;  // h1 dead after gemm2

    int tot  = E + N;                       // 850000
    int nblk = (tot + CH - 1) / CH;         // 208 <= 256
    int nb   = (N + 255) >> 8;              // 196 <= 256

    // CSR build (bucketed counting sort; includes self-loops)
    detect_kernel<<<1, 64, 0, stream>>>((const int*)ei, flag);
    zero_btot_kernel<<<1, 256, 0, stream>>>(btot);
    histA_kernel<<<nblk, 256, 0, stream>>>(ei, flag, blkhist, btot, E, N);
    bucket_scan_kernel<<<1, 256, 0, stream>>>(btot, bbase, nb, tot);
    blk_scan_kernel<<<nb, 256, 0, stream>>>(blkhist, bbase, blkoff, nblk);
    partC_kernel<<<nblk, 256, 0, stream>>>(ei, flag, blkoff, part, E, N);
    csrD_kernel<<<nb, 256, 0, stream>>>(part, bbase, row_ptr, adj, N);
    w3a_kernel<<<1, 128, 0, stream>>>(W3, a3s, a3d, w_as, w_ad);
    w3pad_kernel<<<(64 * 244 + 255) / 256, 256, 0, stream>>>(W3, W3p);

    int nb4 = (N + 3) / 4;
    int nb32 = (N + 31) / 32;

    // Layer 1: x -> XW1h (fp16), agg -> bufB (h1 fp32)
    gemm_alpha_v5<128><<<nb32, 256, 0, stream>>>(x, W1, a1s, a1d, XW1h, As, Ad, N);
    agg_h8c8_v6<false, false><<<nb4, 256, 0, stream>>>((const __half2*)XW1h, As, Ad,
                                                       row_ptr, adj, b1, bufB,
                                                       nullptr, nullptr,
                                                       nullptr, nullptr, N);
    // Layer 2: bufB (fp32) -> XW2h (fp16), agg -> h2h (fp16) + As3/Ad3
    gemm_alpha_v5<64><<<nb32, 256, 0, stream>>>(bufB, W2, a2s, a2d, XW2h, As, Ad, N);
    agg_h8c8_v6<true, true><<<nb4, 256, 0, stream>>>((const __half2*)XW2h, As, Ad,
                                                     row_ptr, adj, b2, h2h,
                                                     w_as, w_ad, As3, Ad3, N);
    // Layer 3: h2h (fp16) -> msg (fp32, bufB), then gemm3 -> out
    agg3msg_v6<<<nb4, 256, 0, stream>>>((const __half2*)h2h, As3, Ad3, row_ptr, adj,
                                        msg, N);
    gemm3_kernel<<<nb32, 256, 0, stream>>>(msg, W3p, b3, out, N);
}

// Round 12
// 344.300 us; speedup vs baseline: 1.2760x; 1.0131x over previous
//
#include <hip/hip_runtime.h>
#include <hip/hip_bf16.h>
#include <hip/hip_fp16.h>

// GAT 3-layer (PPI-style) on MI355X. fp32 tensors; edge_index (2,E) planar,
// int32/int64 via device flag. R20 retry (compile fix only):
// gemm3 was latency-bound (VGPR 60 -> ~4 W loads in flight, VALUBusy 29%,
// occupancy 30%) with partial-line scalar stores. gemm3_v3: (a) 2-deep
// named-register pipeline of W3p k-quads (R14/R19-proven fix); (b) output
// tile staged in LDS (31.2KB, reusing the msh buffer after sync), streamed
// out as dense coalesced 4B-per-lane sequential stores. No runtime-indexed
// private arrays (R17). Fix vs failed R20: G3FMA takes full register names
// as args (token-paste done once in GWCONS) -- 'w##S##2.y' pasted against
// the pp-number '2.y' and formed an invalid token.

#define CH 4096     // items per partition block
#define CAP 8192    // csrD staging capacity (mean bucket = 4352, 60 sigma headroom)

__device__ __forceinline__ float lrelu(float s) { return (s >= 0.f) ? s : 0.2f * s; }

// ---------------- edge dtype detection: (2,E) planar ----------------

__global__ void detect_kernel(const int* __restrict__ ei, int* __restrict__ flag) {
    int t = threadIdx.x;  // 64 lanes
    int v = ei[2 * t + 1];
    unsigned long long b = __ballot(v == 0);
    if (t == 0) *flag = (b == ~0ULL) ? 1 : 0;
}

__device__ __forceinline__ int edge_at(const void* ei, int is64, long long idx) {
    return is64 ? (int)((const long long*)ei)[idx] : ((const int*)ei)[idx];
}

// ---------------- bucketed CSR build ----------------

__global__ void zero_btot_kernel(int* __restrict__ btot) {
    btot[threadIdx.x] = 0;  // 256 threads
}

__global__ __launch_bounds__(256)
void histA_kernel(const void* __restrict__ ei, const int* __restrict__ flag,
                  int* __restrict__ blkhist, int* __restrict__ btot, int E, int N) {
    __shared__ int h[256];
    int t = threadIdx.x;
    h[t] = 0;
    __syncthreads();
    int is64 = *flag;
    long long base = (long long)blockIdx.x * CH;
    long long tot = (long long)E + N;
#pragma unroll
    for (int i = 0; i < CH / 256; ++i) {
        long long idx = base + t + i * 256;
        if (idx < tot) {
            int dst = (idx < E) ? edge_at(ei, is64, (long long)E + idx) : (int)(idx - E);
            atomicAdd(&h[(dst >> 8) & 255], 1);
        }
    }
    __syncthreads();
    int nb = (N + 255) >> 8;
    if (t < nb) {
        blkhist[t * 256 + blockIdx.x] = h[t];
        atomicAdd(&btot[t], h[t]);
    }
}

__global__ __launch_bounds__(256)
void bucket_scan_kernel(const int* __restrict__ btot, int* __restrict__ bbase,
                        int nb, int total) {
    __shared__ int s[256];
    int t = threadIdx.x;
    int v = (t < nb) ? btot[t] : 0;
    s[t] = v;
    __syncthreads();
#pragma unroll
    for (int off = 1; off < 256; off <<= 1) {
        int u = (t >= off) ? s[t - off] : 0;
        __syncthreads();
        s[t] += u;
        __syncthreads();
    }
    if (t < nb) bbase[t] = s[t] - v;
    if (t == 0) bbase[nb] = total;
}

__global__ __launch_bounds__(256)
void blk_scan_kernel(const int* __restrict__ blkhist, const int* __restrict__ bbase,
                     int* __restrict__ blkoff, int nblk) {
    __shared__ int s[256];
    int t = threadIdx.x;
    int b = blockIdx.x;
    int v = (t < nblk) ? blkhist[b * 256 + t] : 0;
    s[t] = v;
    __syncthreads();
#pragma unroll
    for (int off = 1; off < 256; off <<= 1) {
        int u = (t >= off) ? s[t - off] : 0;
        __syncthreads();
        s[t] += u;
        __syncthreads();
    }
    if (t < nblk) blkoff[b * 256 + t] = bbase[b] + s[t] - v;
}

__global__ __launch_bounds__(256)
void partC_kernel(const void* __restrict__ ei, const int* __restrict__ flag,
                  const int* __restrict__ blkoff, int2* __restrict__ part,
                  int E, int N) {
    __shared__ int h[256];
    __shared__ int lst[256];
    __shared__ int cur[256];
    __shared__ int grb[256];
    __shared__ int ssrc[CH];
    __shared__ int sdst[CH];
    int t = threadIdx.x;
    h[t] = 0;
    __syncthreads();
    int is64 = *flag;
    long long base = (long long)blockIdx.x * CH;
    long long tot = (long long)E + N;
    int msrc[CH / 256], mdst[CH / 256], mb[CH / 256];
#pragma unroll
    for (int i = 0; i < CH / 256; ++i) {
        long long idx = base + t + i * 256;
        if (idx < tot) {
            int s, d;
            if (idx < E) {
                s = edge_at(ei, is64, idx);
                d = edge_at(ei, is64, (long long)E + idx);
            } else {
                s = (int)(idx - E);
                d = s;
            }
            msrc[i] = s;
            mdst[i] = d;
            mb[i] = (d >> 8) & 255;
            atomicAdd(&h[mb[i]], 1);
        } else {
            mb[i] = -1;
        }
    }
    __syncthreads();
    int v = h[t];
    lst[t] = v;
    __syncthreads();
#pragma unroll
    for (int off = 1; off < 256; off <<= 1) {
        int u = (t >= off) ? lst[t - off] : 0;
        __syncthreads();
        lst[t] += u;
        __syncthreads();
    }
    int ex = lst[t] - v;
    lst[t] = ex;
    cur[t] = ex;
    int nb = (N + 255) >> 8;
    grb[t] = (t < nb) ? blkoff[t * 256 + blockIdx.x] : 0;
    __syncthreads();
#pragma unroll
    for (int i = 0; i < CH / 256; ++i) {
        if (mb[i] >= 0) {
            int slot = atomicAdd(&cur[mb[i]], 1);
            ssrc[slot] = msrc[i];
            sdst[slot] = mdst[i];
        }
    }
    __syncthreads();
    int items = (int)((tot - base < CH) ? (tot - base) : CH);
    for (int r = t; r < items; r += 256) {
        int d = sdst[r];
        int b = (d >> 8) & 255;
        part[grb[b] + (r - lst[b])] = make_int2(ssrc[r], d);
    }
}

__global__ __launch_bounds__(256)
void csrD_kernel(const int2* __restrict__ part, const int* __restrict__ bbase,
                 int* __restrict__ row_ptr, int* __restrict__ adj, int N) {
    __shared__ int cnt[256];
    __shared__ int lst[256];
    __shared__ int cur[256];
    __shared__ int ssrc[CAP];
    int t = threadIdx.x;
    int b = blockIdx.x;
    int lo = bbase[b], hi = bbase[b + 1];
    int n0 = b << 8;
    cnt[t] = 0;
    __syncthreads();
    for (int r = lo + t; r < hi; r += 256) atomicAdd(&cnt[part[r].y & 255], 1);
    __syncthreads();
    int v = cnt[t];
    lst[t] = v;
    __syncthreads();
#pragma unroll
    for (int off = 1; off < 256; off <<= 1) {
        int u = (t >= off) ? lst[t - off] : 0;
        __syncthreads();
        lst[t] += u;
        __syncthreads();
    }
    int ex = lst[t] - v;
    lst[t] = ex;
    cur[t] = ex;
    __syncthreads();
    if (n0 + t < N) row_ptr[n0 + t] = lo + ex;
    if (b == gridDim.x - 1 && t == 0) row_ptr[N] = hi;
    int items = hi - lo;
    if (items <= CAP) {
        for (int r = lo + t; r < hi; r += 256) {
            int2 p = part[r];
            int slot = atomicAdd(&cur[p.y & 255], 1);
            ssrc[slot] = p.x;
        }
        __syncthreads();
        for (int r = t; r < items; r += 256) adj[lo + r] = ssrc[r];
    } else {  // overflow fallback (never for this dataset): unstaged writes
        for (int r = lo + t; r < hi; r += 256) {
            int2 p = part[r];
            int slot = atomicAdd(&cur[p.y & 255], 1);
            adj[lo + slot] = p.x;
        }
    }
}

// ---- w_as = W3 @ a3_src, w_ad = W3 @ a3_dst; and W3 padded to stride 244 ---

__global__ void w3a_kernel(const float* __restrict__ W3,
                           const float* __restrict__ a3s,
                           const float* __restrict__ a3d,
                           float* __restrict__ w_as, float* __restrict__ w_ad) {
    int t = threadIdx.x;  // 128 threads
    if (t >= 128) return;
    int k = t & 63;
    const float* a = (t < 64) ? a3s : a3d;
    float s = 0.f;
    for (int c = 0; c < 242; ++c) s = fmaf(W3[k * 242 + c], a[c], s);
    if (t < 64) w_as[k] = s; else w_ad[k] = s;
}

__global__ __launch_bounds__(256)
void w3pad_kernel(const float* __restrict__ W3, float* __restrict__ W3p) {
    int t = blockIdx.x * blockDim.x + threadIdx.x;  // 64*244
    if (t >= 64 * 244) return;
    int k = t / 244, c = t - k * 244;
    W3p[t] = (c < 242) ? W3[k * 242 + c] : 0.f;
}

// ---------------- GEMM + alpha (layers 1 & 2) — fp16 XW output -------------

template <int K>
__global__ __launch_bounds__(256)
void gemm_alpha_v5(const float* __restrict__ X, const float* __restrict__ W,
                   const float* __restrict__ a_src, const float* __restrict__ a_dst,
                   __half* __restrict__ XWh, float* __restrict__ As, float* __restrict__ Ad,
                   int N) {
    constexpr int S = K + 4;        // padded LDS row stride (floats)
    constexpr int F4R = K / 4;      // float4 per row
    __shared__ float xs[32][S];
    int t = threadIdx.x;
    int block0 = blockIdx.x * 32;

    for (int i = t; i < 32 * F4R; i += 256) {
        int row = i / F4R, c4 = i - row * F4R;
        int node = block0 + row;
        float4 v = (node < N) ? *(const float4*)(X + (size_t)node * K + c4 * 4)
                              : make_float4(0.f, 0.f, 0.f, 0.f);
        *(float4*)(&xs[row][c4 * 4]) = v;
    }
    __syncthreads();

    int wave = t >> 6, lane = t & 63;
    int jj = lane >> 4, cc = lane & 15;
    int r0 = wave * 8 + jj * 2;     // local node pair
    int base = block0 + r0;

    float4 o0 = make_float4(0.f, 0.f, 0.f, 0.f);
    float4 o1 = make_float4(0.f, 0.f, 0.f, 0.f);

    const float* wp = W + cc * 4;
#pragma unroll 2
    for (int k = 0; k < K; k += 4) {
        float4 w0 = *(const float4*)(wp + (size_t)(k + 0) * 64);
        float4 w1 = *(const float4*)(wp + (size_t)(k + 1) * 64);
        float4 w2 = *(const float4*)(wp + (size_t)(k + 2) * 64);
        float4 w3 = *(const float4*)(wp + (size_t)(k + 3) * 64);
        float4 m0 = *(const float4*)(&xs[r0][k]);
        float4 m1 = *(const float4*)(&xs[r0 + 1][k]);

        o0.x = fmaf(m0.x, w0.x, o0.x);
        o0.y = fmaf(m0.x, w0.y, o0.y);
        o0.z = fmaf(m0.x, w0.z, o0.z);
        o0.w = fmaf(m0.x, w0.w, o0.w);
        o0.x = fmaf(m0.y, w1.x, o0.x);
        o0.y = fmaf(m0.y, w1.y, o0.y);
        o0.z = fmaf(m0.y, w1.z, o0.z);
        o0.w = fmaf(m0.y, w1.w, o0.w);
        o0.x = fmaf(m0.z, w2.x, o0.x);
        o0.y = fmaf(m0.z, w2.y, o0.y);
        o0.z = fmaf(m0.z, w2.z, o0.z);
        o0.w = fmaf(m0.z, w2.w, o0.w);
        o0.x = fmaf(m0.w, w3.x, o0.x);
        o0.y = fmaf(m0.w, w3.y, o0.y);
        o0.z = fmaf(m0.w, w3.z, o0.z);
        o0.w = fmaf(m0.w, w3.w, o0.w);

        o1.x = fmaf(m1.x, w0.x, o1.x);
        o1.y = fmaf(m1.x, w0.y, o1.y);
        o1.z = fmaf(m1.x, w0.z, o1.z);
        o1.w = fmaf(m1.x, w0.w, o1.w);
        o1.x = fmaf(m1.y, w1.x, o1.x);
        o1.y = fmaf(m1.y, w1.y, o1.y);
        o1.z = fmaf(m1.y, w1.z, o1.z);
        o1.w = fmaf(m1.y, w1.w, o1.w);
        o1.x = fmaf(m1.z, w2.x, o1.x);
        o1.y = fmaf(m1.z, w2.y, o1.y);
        o1.z = fmaf(m1.z, w2.z, o1.z);
        o1.w = fmaf(m1.z, w2.w, o1.w);
        o1.x = fmaf(m1.w, w3.x, o1.x);
        o1.y = fmaf(m1.w, w3.y, o1.y);
        o1.z = fmaf(m1.w, w3.z, o1.z);
        o1.w = fmaf(m1.w, w3.w, o1.w);
    }

    float4 av = *(const float4*)(a_src + cc * 4);
    float4 dv = *(const float4*)(a_dst + cc * 4);

    if (base < N) {
        union { __half2 h[2]; uint2 u; } pk;
        pk.h[0] = __floats2half2_rn(o0.x, o0.y);
        pk.h[1] = __floats2half2_rn(o0.z, o0.w);
        *(uint2*)(XWh + (size_t)base * 64 + cc * 4) = pk.u;
        float s = o0.x * av.x + o0.y * av.y + o0.z * av.z + o0.w * av.w;
        float d = o0.x * dv.x + o0.y * dv.y + o0.z * dv.z + o0.w * dv.w;
        s += __shfl_xor(s, 1);
        d += __shfl_xor(d, 1);
        if ((cc & 1) == 0) {
            As[base * 8 + (cc >> 1)] = s;
            Ad[base * 8 + (cc >> 1)] = d;
        }
    }
    if (base + 1 < N) {
        union { __half2 h[2]; uint2 u; } pk;
        pk.h[0] = __floats2half2_rn(o1.x, o1.y);
        pk.h[1] = __floats2half2_rn(o1.z, o1.w);
        *(uint2*)(XWh + (size_t)(base + 1) * 64 + cc * 4) = pk.u;
        float s = o1.x * av.x + o1.y * av.y + o1.z * av.z + o1.w * av.w;
        float d = o1.x * dv.x + o1.y * dv.y + o1.z * dv.z + o1.w * dv.w;
        s += __shfl_xor(s, 1);
        d += __shfl_xor(d, 1);
        if ((cc & 1) == 0) {
            As[(base + 1) * 8 + (cc >> 1)] = s;
            Ad[(base + 1) * 8 + (cc >> 1)] = d;
        }
    }
}

// ---------------- Aggregation v6 (layers 1 & 2: H=8, C=8) ------------------
// 2-deep software pipeline over clamped 16-edge chunks (register sets A/B).

#define AISSUE(S, KK)                                                          \
    {                                                                          \
        int b_ = beg + ((KK) << 4);                                            \
        int lim_ = end - 1;                                                    \
        int ia_ = b_ + eP; ia_ = (ia_ < lim_) ? ia_ : lim_;                    \
        int ib_ = b_ + 8 + eP; ib_ = (ib_ < lim_) ? ib_ : lim_;                \
        int sa_ = adj[ia_];                                                    \
        int sb_ = adj[ib_];                                                    \
        asa##S = As[(size_t)sa_ * 8 + hP];                                     \
        asb##S = As[(size_t)sb_ * 8 + hP];                                     \
        ALD(S, 0, b_, lim_) ALD(S, 1, b_, lim_) ALD(S, 2, b_, lim_)            \
        ALD(S, 3, b_, lim_) ALD(S, 4, b_, lim_) ALD(S, 5, b_, lim_)            \
        ALD(S, 6, b_, lim_) ALD(S, 7, b_, lim_)                                \
    }

#define ALD(S, J, B, LIM)                                                      \
    {                                                                          \
        int i0_ = (B) + 2 * (J); i0_ = (i0_ < (LIM)) ? i0_ : (LIM);            \
        int i1_ = (B) + 2 * (J) + 1; i1_ = (i1_ < (LIM)) ? i1_ : (LIM);        \
        int e0_ = adj[i0_];                                                    \
        int e1_ = adj[i1_];                                                    \
        int row_ = r ? e1_ : e0_;                                              \
        g##S##J = XW[(size_t)row_ * 32 + c2];                                  \
    }

#define ACONS(S, KK)                                                           \
    {                                                                          \
        int b_ = beg + ((KK) << 4);                                            \
        float pa_ = (b_ + eP < end) ? __expf(lrelu(asa##S + adp)) : 0.f;       \
        float pb_ = (b_ + 8 + eP < end) ? __expf(lrelu(asb##S + adp)) : 0.f;   \
        den_part += pa_ + pb_;                                                 \
        APC(S, 0, pa_) APC(S, 1, pa_) APC(S, 2, pa_) APC(S, 3, pa_)            \
        APC(S, 4, pb_) APC(S, 5, pb_) APC(S, 6, pb_) APC(S, 7, pb_)            \
    }

#define APC(S, J, P)                                                           \
    {                                                                          \
        float2 xv_ = __half22float2(g##S##J);                                  \
        float pk_ = __shfl((P), (((2 * (J)) & 7) + r) * 8 + hA);               \
        accx = fmaf(pk_, xv_.x, accx);                                         \
        accy = fmaf(pk_, xv_.y, accy);                                         \
    }

template <bool WITH_A3, bool HALF_OUT>
__global__ __launch_bounds__(256)
void agg_h8c8_v6(const __half2* __restrict__ XW, const float* __restrict__ As,
                 const float* __restrict__ Ad, const int* __restrict__ row_ptr,
                 const int* __restrict__ adj, const float* __restrict__ bias,
                 void* __restrict__ OUTv,
                 const float* __restrict__ w_as, const float* __restrict__ w_ad,
                 float* __restrict__ As3, float* __restrict__ Ad3, int N) {
    int wave = threadIdx.x >> 6, lane = threadIdx.x & 63;
    int node = blockIdx.x * 4 + wave;
    if (node >= N) return;
    int beg = row_ptr[node], end = row_ptr[node + 1];
    int eP = lane >> 3, hP = lane & 7;     // p-phase coords
    int r = lane >> 5, c2 = lane & 31;     // acc-phase coords
    int hA = c2 >> 2;                      // head of channels (2c2, 2c2+1)
    float adp = Ad[node * 8 + hP];

    float den_part = 0.f;
    float accx = 0.f, accy = 0.f;
    float asaA, asbA, asaB, asbB;
    __half2 gA0, gA1, gA2, gA3, gA4, gA5, gA6, gA7;
    __half2 gB0, gB1, gB2, gB3, gB4, gB5, gB6, gB7;

    int T = (end - beg + 15) >> 4;   // >= 1 (self-loops guarantee deg >= 1)
    AISSUE(A, 0)
    int k = 0;
    while (k + 2 < T) {
        AISSUE(B, k + 1)
        ACONS(A, k)
        AISSUE(A, k + 2)
        ACONS(B, k + 1)
        k += 2;
    }
    if (k + 1 < T) {
        AISSUE(B, k + 1)
        ACONS(A, k)
        ACONS(B, k + 1)
    } else {
        ACONS(A, k)
    }

    // combine edge-parity halves: lane i and i+32 hold the same channels
    accx += __shfl_xor(accx, 32);
    accy += __shfl_xor(accy, 32);
    // den: sum over e-slots, lane holds den[lane&7]; route den[hA] to acc lane
    den_part += __shfl_xor(den_part, 8);
    den_part += __shfl_xor(den_part, 16);
    den_part += __shfl_xor(den_part, 32);
    float den = __shfl(den_part, hA);

    float rden = 1.f / (den + 1e-16f);
    float vx = fmaxf(accx * rden + bias[c2 * 2], 0.f);
    float vy = fmaxf(accy * rden + bias[c2 * 2 + 1], 0.f);
    if (r == 0) {
        if (HALF_OUT) ((__half2*)OUTv)[(size_t)node * 32 + c2] = __floats2half2_rn(vx, vy);
        else          ((float2*)OUTv)[(size_t)node * 32 + c2] = make_float2(vx, vy);
    }

    if (WITH_A3) {
        // all lanes hold channel sums (lane i == lane i+32); reduce lanes 0..31
        float s3v = vx * w_as[c2 * 2] + vy * w_as[c2 * 2 + 1];
        float d3v = vx * w_ad[c2 * 2] + vy * w_ad[c2 * 2 + 1];
#pragma unroll
        for (int m = 1; m <= 16; m <<= 1) {
            s3v += __shfl_xor(s3v, m);
            d3v += __shfl_xor(d3v, m);
        }
        if (lane == 0) {
            As3[node] = s3v;
            Ad3[node] = d3v;
        }
    }
}

// ---------------- Layer 3 aggregation v6 (H=1, 64 cols) --------------------

#define BISSUE(S, KK)                                                          \
    {                                                                          \
        int b_ = beg + ((KK) << 4);                                            \
        int lim_ = end - 1;                                                    \
        int ie_ = b_ + eP3; ie_ = (ie_ < lim_) ? ie_ : lim_;                   \
        int se_ = adj[ie_];                                                    \
        as3##S = As3[se_];                                                     \
        BLD(S, 0, b_, lim_) BLD(S, 1, b_, lim_) BLD(S, 2, b_, lim_)            \
        BLD(S, 3, b_, lim_) BLD(S, 4, b_, lim_) BLD(S, 5, b_, lim_)            \
        BLD(S, 6, b_, lim_) BLD(S, 7, b_, lim_)                                \
    }

#define BLD(S, J, B, LIM)                                                      \
    {                                                                          \
        int i0_ = (B) + 2 * (J); i0_ = (i0_ < (LIM)) ? i0_ : (LIM);            \
        int i1_ = (B) + 2 * (J) + 1; i1_ = (i1_ < (LIM)) ? i1_ : (LIM);        \
        int e0_ = adj[i0_];                                                    \
        int e1_ = adj[i1_];                                                    \
        int row_ = r ? e1_ : e0_;                                              \
        q##S##J = H2[(size_t)row_ * 32 + c2];                                  \
    }

#define BCONS(S, KK)                                                           \
    {                                                                          \
        int b_ = beg + ((KK) << 4);                                            \
        float p_ = (b_ + eP3 < end) ? __expf(lrelu(as3##S + ad)) : 0.f;        \
        den_part += p_;                                                        \
        BPC(S, 0, p_) BPC(S, 1, p_) BPC(S, 2, p_) BPC(S, 3, p_)                \
        BPC(S, 4, p_) BPC(S, 5, p_) BPC(S, 6, p_) BPC(S, 7, p_)                \
    }

#define BPC(S, J, P)                                                           \
    {                                                                          \
        float2 xv_ = __half22float2(q##S##J);                                  \
        float pk_ = __shfl((P), 2 * (J) + r);                                  \
        accx = fmaf(pk_, xv_.x, accx);                                         \
        accy = fmaf(pk_, xv_.y, accy);                                         \
    }

__global__ __launch_bounds__(256)
void agg3msg_v6(const __half2* __restrict__ H2, const float* __restrict__ As3,
                const float* __restrict__ Ad3, const int* __restrict__ row_ptr,
                const int* __restrict__ adj, float* __restrict__ MSG, int N) {
    int wave = threadIdx.x >> 6, lane = threadIdx.x & 63;
    int node = blockIdx.x * 4 + wave;
    if (node >= N) return;
    int beg = row_ptr[node], end = row_ptr[node + 1];
    float ad = Ad3[node];
    int eP3 = lane & 15;
    int r = lane >> 5, c2 = lane & 31;

    float den_part = 0.f;
    float accx = 0.f, accy = 0.f;
    float as3A, as3B;
    __half2 qA0, qA1, qA2, qA3, qA4, qA5, qA6, qA7;
    __half2 qB0, qB1, qB2, qB3, qB4, qB5, qB6, qB7;

    int T = (end - beg + 15) >> 4;
    BISSUE(A, 0)
    int k = 0;
    while (k + 2 < T) {
        BISSUE(B, k + 1)
        BCONS(A, k)
        BISSUE(A, k + 2)
        BCONS(B, k + 1)
        k += 2;
    }
    if (k + 1 < T) {
        BISSUE(B, k + 1)
        BCONS(A, k)
        BCONS(B, k + 1)
    } else {
        BCONS(A, k)
    }

    accx += __shfl_xor(accx, 32);
    accy += __shfl_xor(accy, 32);
    den_part += __shfl_xor(den_part, 1);
    den_part += __shfl_xor(den_part, 2);
    den_part += __shfl_xor(den_part, 4);
    den_part += __shfl_xor(den_part, 8);  // every lane: full den
    float rden = 1.f / (den_part + 1e-16f);
    if (r == 0) {
        ((float2*)MSG)[(size_t)node * 32 + c2] = make_float2(accx * rden, accy * rden);
    }
}

// ---------------- gemm3 v3: OUT = softmax_pairs(relu(MSG @ W3 + b3)) -------
// (a) 2-deep named-register pipeline of W3p k-quads (A/B sets);
// (b) 32x242 output tile staged in LDS (reuses the msh buffer after sync)
//     then streamed out as dense 4B-per-lane sequential stores.
// G3FMA takes full register identifiers as arguments; token-pasting happens
// only in GWCONS (never adjacent to a member access -> no pp-number hazard).

#define G3FMA(WR0, WR1, WR2, WR3, J, KK)                                       \
    {                                                                          \
        float4 m_ = *(const float4*)(sh + wave * 512 + (J) * 64 + (KK));       \
        o[J][0] = fmaf(m_.x, (WR0).x, o[J][0]);                                \
        o[J][1] = fmaf(m_.x, (WR0).y, o[J][1]);                                \
        o[J][2] = fmaf(m_.x, (WR0).z, o[J][2]);                                \
        o[J][3] = fmaf(m_.x, (WR0).w, o[J][3]);                                \
        o[J][0] = fmaf(m_.y, (WR1).x, o[J][0]);                                \
        o[J][1] = fmaf(m_.y, (WR1).y, o[J][1]);                                \
        o[J][2] = fmaf(m_.y, (WR1).z, o[J][2]);                                \
        o[J][3] = fmaf(m_.y, (WR1).w, o[J][3]);                                \
        o[J][0] = fmaf(m_.z, (WR2).x, o[J][0]);                                \
        o[J][1] = fmaf(m_.z, (WR2).y, o[J][1]);                                \
        o[J][2] = fmaf(m_.z, (WR2).z, o[J][2]);                                \
        o[J][3] = fmaf(m_.z, (WR2).w, o[J][3]);                                \
        o[J][0] = fmaf(m_.w, (WR3).x, o[J][0]);                                \
        o[J][1] = fmaf(m_.w, (WR3).y, o[J][1]);                                \
        o[J][2] = fmaf(m_.w, (WR3).z, o[J][2]);                                \
        o[J][3] = fmaf(m_.w, (WR3).w, o[J][3]);                                \
    }

#define GWLD(S, KK)                                                            \
    {                                                                          \
        const float* wp_ = W3p + (size_t)(KK) * 244 + c0;                      \
        w##S##0 = *(const float4*)(wp_);                                       \
        w##S##1 = *(const float4*)(wp_ + 244);                                 \
        w##S##2 = *(const float4*)(wp_ + 488);                                 \
        w##S##3 = *(const float4*)(wp_ + 732);                                 \
    }

#define GWCONS(S, KK)                                                          \
    G3FMA(w##S##0, w##S##1, w##S##2, w##S##3, 0, KK)                           \
    G3FMA(w##S##0, w##S##1, w##S##2, w##S##3, 1, KK)                           \
    G3FMA(w##S##0, w##S##1, w##S##2, w##S##3, 2, KK)                           \
    G3FMA(w##S##0, w##S##1, w##S##2, w##S##3, 3, KK)                           \
    G3FMA(w##S##0, w##S##1, w##S##2, w##S##3, 4, KK)                           \
    G3FMA(w##S##0, w##S##1, w##S##2, w##S##3, 5, KK)                           \
    G3FMA(w##S##0, w##S##1, w##S##2, w##S##3, 6, KK)                           \
    G3FMA(w##S##0, w##S##1, w##S##2, w##S##3, 7, KK)

__global__ __launch_bounds__(256)
void gemm3_v3(const float* __restrict__ MSG, const float* __restrict__ W3p,
              const float* __restrict__ bias, float* __restrict__ OUT, int N) {
    __shared__ float sh[32 * 244];  // 31232 B
    int t = threadIdx.x;
    int wave = t >> 6, lane = t & 63;
    int block0 = blockIdx.x * 32;

    // stage MSG into msh region (per-wave; same-wave LDS RAW, DS in-order)
#pragma unroll
    for (int j = 0; j < 8; ++j) {
        int node = block0 + wave * 8 + j;
        sh[wave * 512 + j * 64 + lane] =
            (node < N) ? MSG[(size_t)node * 64 + lane] : 0.f;
    }

    int c0 = lane * 4;  // lanes 0..60 carry channels; 61-63 idle in compute
    float o[8][4];
    if (c0 < 242) {
#pragma unroll
        for (int j = 0; j < 8; ++j)
#pragma unroll
            for (int q = 0; q < 4; ++q) o[j][q] = 0.f;

        float4 wA0, wA1, wA2, wA3, wB0, wB1, wB2, wB3;
        GWLD(A, 0)
#pragma unroll
        for (int k = 0; k < 64; k += 8) {
            GWLD(B, k + 4)
            GWCONS(A, k)
            if (k + 8 < 64) { GWLD(A, k + 8) }
            GWCONS(B, k + 4)
        }
    }
    __syncthreads();  // all msh reads complete before tile overwrites

    if (c0 < 242) {
        float b0 = bias[c0], b1v = bias[c0 + 1];
        float b2v = (c0 + 2 < 242) ? bias[c0 + 2] : 0.f;
        float b3v = (c0 + 3 < 242) ? bias[c0 + 3] : 0.f;
#pragma unroll
        for (int j = 0; j < 8; ++j) {
            float v0 = fmaxf(o[j][0] + b0, 0.f);
            float v1 = fmaxf(o[j][1] + b1v, 0.f);
            float m01 = fmaxf(v0, v1);
            float e0 = __expf(v0 - m01), e1 = __expf(v1 - m01);
            float r01 = 1.f / (e0 + e1);
            float q0 = e0 * r01, q1 = e1 * r01, q2 = 0.f, q3 = 0.f;
            if (c0 + 2 < 242) {
                float v2 = fmaxf(o[j][2] + b2v, 0.f);
                float v3 = fmaxf(o[j][3] + b3v, 0.f);
                float m23 = fmaxf(v2, v3);
                float e2 = __expf(v2 - m23), e3 = __expf(v3 - m23);
                float r23 = 1.f / (e2 + e3);
                q2 = e2 * r23;
                q3 = e3 * r23;
            }
            int jn = wave * 8 + j;
            // byte offset jn*976 + lane*16: 16B-aligned (976 % 16 == 0)
            *(float4*)(&sh[jn * 244 + c0]) = make_float4(q0, q1, q2, q3);
        }
    }
    __syncthreads();

    // dense coalesced copy: block's rows are contiguous in OUT
    int rows = N - block0;
    if (rows > 32) rows = 32;
    int nf = rows * 242;
    size_t gbase = (size_t)block0 * 242;
    for (int f = t; f < nf; f += 256) {
        int row = f / 242;           // compile-time-constant divisor -> magic mul
        int col = f - row * 242;
        OUT[gbase + f] = sh[row * 244 + col];
    }
}

// ---------------- launch ----------------

extern "C" void kernel_launch(void* const* d_in, const int* in_sizes, int n_in,
                              void* d_out, int out_size, void* d_ws, size_t ws_size,
                              hipStream_t stream) {
    const float* x   = (const float*)d_in[0];
    const void*  ei  = d_in[1];
    const float* W1  = (const float*)d_in[2];
    const float* a1s = (const float*)d_in[3];
    const float* a1d = (const float*)d_in[4];
    const float* b1  = (const float*)d_in[5];
    const float* W2  = (const float*)d_in[6];
    const float* a2s = (const float*)d_in[7];
    const float* a2d = (const float*)d_in[8];
    const float* b2  = (const float*)d_in[9];
    const float* W3  = (const float*)d_in[10];
    const float* a3s = (const float*)d_in[11];
    const float* a3d = (const float*)d_in[12];
    const float* b3  = (const float*)d_in[13];
    float* out = (float*)d_out;

    const int N = in_sizes[0] / 128;  // 50000
    const int E = in_sizes[1] / 2;    // 800000

    char* w = (char*)d_ws;
    auto alloc = [&](size_t bytes) {
        char* p = w;
        w += (bytes + 255) & ~(size_t)255;
        return p;
    };
    int*   flag    = (int*)alloc(4);
    int*   row_ptr = (int*)alloc(((size_t)N + 1) * 4);
    int*   adj     = (int*)alloc((size_t)(E + N) * 4);
    int*   btot    = (int*)alloc(256 * 4);
    int*   bbase   = (int*)alloc(257 * 4);
    float* As      = (float*)alloc((size_t)N * 8 * 4);
    float* Ad      = (float*)alloc((size_t)N * 8 * 4);
    float* As3     = (float*)alloc((size_t)N * 4);
    float* Ad3     = (float*)alloc((size_t)N * 4);
    float* w_as    = (float*)alloc(64 * 4);
    float* w_ad    = (float*)alloc(64 * 4);
    float* W3p     = (float*)alloc((size_t)64 * 244 * 4);
    float* bufA    = (float*)alloc((size_t)N * 64 * 4);
    float* bufB    = (float*)alloc((size_t)N * 64 * 4);
    // CSR scratch aliased into bufA (12.8MB): part 6.8MB @0, blkhist 256KB @7MB,
    // blkoff 256KB @7.25MB. All dead before gemm1 first writes bufA.
    int2*   part    = (int2*)bufA;
    int*    blkhist = (int*)((char*)bufA + (size_t)7 * 1024 * 1024);
    int*    blkoff  = (int*)((char*)bufA + (size_t)7 * 1024 * 1024 + 256 * 1024);
    // fp16 buffers aliased into bufA (lifetimes disjoint):
    //   XW1h @ bufA[0:6.4e6)        (gemm1 -> agg1)
    //   XW2h @ bufA[6.4e6:12.8e6)   (gemm2 -> agg2)
    //   h2h  @ bufA[0:6.4e6)        (agg2 -> agg3; XW1h dead)
    __half* XW1h = (__half*)bufA;
    __half* XW2h = (__half*)((char*)bufA + (size_t)N * 64 * 2);
    __half* h2h  = (__half*)bufA;
    float*  msg  = bufB;  // h1 dead after gemm2

    int tot  = E + N;                       // 850000
    int nblk = (tot + CH - 1) / CH;         // 208 <= 256
    int nb   = (N + 255) >> 8;              // 196 <= 256

    // CSR build (bucketed counting sort; includes self-loops)
    detect_kernel<<<1, 64, 0, stream>>>((const int*)ei, flag);
    zero_btot_kernel<<<1, 256, 0, stream>>>(btot);
    histA_kernel<<<nblk, 256, 0, stream>>>(ei, flag, blkhist, btot, E, N);
    bucket_scan_kernel<<<1, 256, 0, stream>>>(btot, bbase, nb, tot);
    blk_scan_kernel<<<nb, 256, 0, stream>>>(blkhist, bbase, blkoff, nblk);
    partC_kernel<<<nblk, 256, 0, stream>>>(ei, flag, blkoff, part, E, N);
    csrD_kernel<<<nb, 256, 0, stream>>>(part, bbase, row_ptr, adj, N);
    w3a_kernel<<<1, 128, 0, stream>>>(W3, a3s, a3d, w_as, w_ad);
    w3pad_kernel<<<(64 * 244 + 255) / 256, 256, 0, stream>>>(W3, W3p);

    int nb4 = (N + 3) / 4;
    int nb32 = (N + 31) / 32;

    // Layer 1: x -> XW1h (fp16), agg -> bufB (h1 fp32)
    gemm_alpha_v5<128><<<nb32, 256, 0, stream>>>(x, W1, a1s, a1d, XW1h, As, Ad, N);
    agg_h8c8_v6<false, false><<<nb4, 256, 0, stream>>>((const __half2*)XW1h, As, Ad,
                                                       row_ptr, adj, b1, bufB,
                                                       nullptr, nullptr,
                                                       nullptr, nullptr, N);
    // Layer 2: bufB (fp32) -> XW2h (fp16), agg -> h2h (fp16) + As3/Ad3
    gemm_alpha_v5<64><<<nb32, 256, 0, stream>>>(bufB, W2, a2s, a2d, XW2h, As, Ad, N);
    agg_h8c8_v6<true, true><<<nb4, 256, 0, stream>>>((const __half2*)XW2h, As, Ad,
                                                     row_ptr, adj, b2, h2h,
                                                     w_as, w_ad, As3, Ad3, N);
    // Layer 3: h2h (fp16) -> msg (fp32, bufB), then gemm3 v3 -> out
    agg3msg_v6<<<nb4, 256, 0, stream>>>((const __half2*)h2h, As3, Ad3, row_ptr, adj,
                                        msg, N);
    gemm3_v3<<<nb32, 256, 0, stream>>>(msg, W3p, b3, out, N);
}

// Round 14
// 319.916 us; speedup vs baseline: 1.3732x; 1.0762x over previous
//
#include <hip/hip_runtime.h>
#include <hip/hip_bf16.h>
#include <hip/hip_fp16.h>

// GAT 3-layer (PPI-style) on MI355X. fp32 tensors; edge_index (2,E) planar,
// int32/int64 via device flag. R21 resubmit (R21 audit found no on-device
// fault; container failure matched R13's infra-flake signature):
// agg v6 pipeline raised VALUBusy to 62% but issued 28 VMEM/chunk (16 were
// 64-lane broadcast adj loads) + heavy clamp VALU. v7: adj distributed
// across lanes once per chunk (the p-phase loads), row indices obtained via
// __shfl (DS pipe) -> 12 VMEM/chunk; clamping only in the last (partial)
// chunk via wave-uniform branch. No runtime-indexed private arrays (R17).

#define CH 4096     // items per partition block
#define CAP 8192    // csrD staging capacity (mean bucket = 4352, 60 sigma headroom)

__device__ __forceinline__ float lrelu(float s) { return (s >= 0.f) ? s : 0.2f * s; }

// ---------------- edge dtype detection: (2,E) planar ----------------

__global__ void detect_kernel(const int* __restrict__ ei, int* __restrict__ flag) {
    int t = threadIdx.x;  // 64 lanes
    int v = ei[2 * t + 1];
    unsigned long long b = __ballot(v == 0);
    if (t == 0) *flag = (b == ~0ULL) ? 1 : 0;
}

__device__ __forceinline__ int edge_at(const void* ei, int is64, long long idx) {
    return is64 ? (int)((const long long*)ei)[idx] : ((const int*)ei)[idx];
}

// ---------------- bucketed CSR build ----------------

__global__ void zero_btot_kernel(int* __restrict__ btot) {
    btot[threadIdx.x] = 0;  // 256 threads
}

__global__ __launch_bounds__(256)
void histA_kernel(const void* __restrict__ ei, const int* __restrict__ flag,
                  int* __restrict__ blkhist, int* __restrict__ btot, int E, int N) {
    __shared__ int h[256];
    int t = threadIdx.x;
    h[t] = 0;
    __syncthreads();
    int is64 = *flag;
    long long base = (long long)blockIdx.x * CH;
    long long tot = (long long)E + N;
#pragma unroll
    for (int i = 0; i < CH / 256; ++i) {
        long long idx = base + t + i * 256;
        if (idx < tot) {
            int dst = (idx < E) ? edge_at(ei, is64, (long long)E + idx) : (int)(idx - E);
            atomicAdd(&h[(dst >> 8) & 255], 1);
        }
    }
    __syncthreads();
    int nb = (N + 255) >> 8;
    if (t < nb) {
        blkhist[t * 256 + blockIdx.x] = h[t];
        atomicAdd(&btot[t], h[t]);
    }
}

__global__ __launch_bounds__(256)
void bucket_scan_kernel(const int* __restrict__ btot, int* __restrict__ bbase,
                        int nb, int total) {
    __shared__ int s[256];
    int t = threadIdx.x;
    int v = (t < nb) ? btot[t] : 0;
    s[t] = v;
    __syncthreads();
#pragma unroll
    for (int off = 1; off < 256; off <<= 1) {
        int u = (t >= off) ? s[t - off] : 0;
        __syncthreads();
        s[t] += u;
        __syncthreads();
    }
    if (t < nb) bbase[t] = s[t] - v;
    if (t == 0) bbase[nb] = total;
}

__global__ __launch_bounds__(256)
void blk_scan_kernel(const int* __restrict__ blkhist, const int* __restrict__ bbase,
                     int* __restrict__ blkoff, int nblk) {
    __shared__ int s[256];
    int t = threadIdx.x;
    int b = blockIdx.x;
    int v = (t < nblk) ? blkhist[b * 256 + t] : 0;
    s[t] = v;
    __syncthreads();
#pragma unroll
    for (int off = 1; off < 256; off <<= 1) {
        int u = (t >= off) ? s[t - off] : 0;
        __syncthreads();
        s[t] += u;
        __syncthreads();
    }
    if (t < nblk) blkoff[b * 256 + t] = bbase[b] + s[t] - v;
}

__global__ __launch_bounds__(256)
void partC_kernel(const void* __restrict__ ei, const int* __restrict__ flag,
                  const int* __restrict__ blkoff, int2* __restrict__ part,
                  int E, int N) {
    __shared__ int h[256];
    __shared__ int lst[256];
    __shared__ int cur[256];
    __shared__ int grb[256];
    __shared__ int ssrc[CH];
    __shared__ int sdst[CH];
    int t = threadIdx.x;
    h[t] = 0;
    __syncthreads();
    int is64 = *flag;
    long long base = (long long)blockIdx.x * CH;
    long long tot = (long long)E + N;
    int msrc[CH / 256], mdst[CH / 256], mb[CH / 256];
#pragma unroll
    for (int i = 0; i < CH / 256; ++i) {
        long long idx = base + t + i * 256;
        if (idx < tot) {
            int s, d;
            if (idx < E) {
                s = edge_at(ei, is64, idx);
                d = edge_at(ei, is64, (long long)E + idx);
            } else {
                s = (int)(idx - E);
                d = s;
            }
            msrc[i] = s;
            mdst[i] = d;
            mb[i] = (d >> 8) & 255;
            atomicAdd(&h[mb[i]], 1);
        } else {
            mb[i] = -1;
        }
    }
    __syncthreads();
    int v = h[t];
    lst[t] = v;
    __syncthreads();
#pragma unroll
    for (int off = 1; off < 256; off <<= 1) {
        int u = (t >= off) ? lst[t - off] : 0;
        __syncthreads();
        lst[t] += u;
        __syncthreads();
    }
    int ex = lst[t] - v;
    lst[t] = ex;
    cur[t] = ex;
    int nb = (N + 255) >> 8;
    grb[t] = (t < nb) ? blkoff[t * 256 + blockIdx.x] : 0;
    __syncthreads();
#pragma unroll
    for (int i = 0; i < CH / 256; ++i) {
        if (mb[i] >= 0) {
            int slot = atomicAdd(&cur[mb[i]], 1);
            ssrc[slot] = msrc[i];
            sdst[slot] = mdst[i];
        }
    }
    __syncthreads();
    int items = (int)((tot - base < CH) ? (tot - base) : CH);
    for (int r = t; r < items; r += 256) {
        int d = sdst[r];
        int b = (d >> 8) & 255;
        part[grb[b] + (r - lst[b])] = make_int2(ssrc[r], d);
    }
}

__global__ __launch_bounds__(256)
void csrD_kernel(const int2* __restrict__ part, const int* __restrict__ bbase,
                 int* __restrict__ row_ptr, int* __restrict__ adj, int N) {
    __shared__ int cnt[256];
    __shared__ int lst[256];
    __shared__ int cur[256];
    __shared__ int ssrc[CAP];
    int t = threadIdx.x;
    int b = blockIdx.x;
    int lo = bbase[b], hi = bbase[b + 1];
    int n0 = b << 8;
    cnt[t] = 0;
    __syncthreads();
    for (int r = lo + t; r < hi; r += 256) atomicAdd(&cnt[part[r].y & 255], 1);
    __syncthreads();
    int v = cnt[t];
    lst[t] = v;
    __syncthreads();
#pragma unroll
    for (int off = 1; off < 256; off <<= 1) {
        int u = (t >= off) ? lst[t - off] : 0;
        __syncthreads();
        lst[t] += u;
        __syncthreads();
    }
    int ex = lst[t] - v;
    lst[t] = ex;
    cur[t] = ex;
    __syncthreads();
    if (n0 + t < N) row_ptr[n0 + t] = lo + ex;
    if (b == gridDim.x - 1 && t == 0) row_ptr[N] = hi;
    int items = hi - lo;
    if (items <= CAP) {
        for (int r = lo + t; r < hi; r += 256) {
            int2 p = part[r];
            int slot = atomicAdd(&cur[p.y & 255], 1);
            ssrc[slot] = p.x;
        }
        __syncthreads();
        for (int r = t; r < items; r += 256) adj[lo + r] = ssrc[r];
    } else {  // overflow fallback (never for this dataset): unstaged writes
        for (int r = lo + t; r < hi; r += 256) {
            int2 p = part[r];
            int slot = atomicAdd(&cur[p.y & 255], 1);
            adj[lo + slot] = p.x;
        }
    }
}

// ---- w_as = W3 @ a3_src, w_ad = W3 @ a3_dst; and W3 padded to stride 244 ---

__global__ void w3a_kernel(const float* __restrict__ W3,
                           const float* __restrict__ a3s,
                           const float* __restrict__ a3d,
                           float* __restrict__ w_as, float* __restrict__ w_ad) {
    int t = threadIdx.x;  // 128 threads
    if (t >= 128) return;
    int k = t & 63;
    const float* a = (t < 64) ? a3s : a3d;
    float s = 0.f;
    for (int c = 0; c < 242; ++c) s = fmaf(W3[k * 242 + c], a[c], s);
    if (t < 64) w_as[k] = s; else w_ad[k] = s;
}

__global__ __launch_bounds__(256)
void w3pad_kernel(const float* __restrict__ W3, float* __restrict__ W3p) {
    int t = blockIdx.x * blockDim.x + threadIdx.x;  // 64*244
    if (t >= 64 * 244) return;
    int k = t / 244, c = t - k * 244;
    W3p[t] = (c < 242) ? W3[k * 242 + c] : 0.f;
}

// ---------------- GEMM + alpha (layers 1 & 2) — fp16 XW output -------------

template <int K>
__global__ __launch_bounds__(256)
void gemm_alpha_v5(const float* __restrict__ X, const float* __restrict__ W,
                   const float* __restrict__ a_src, const float* __restrict__ a_dst,
                   __half* __restrict__ XWh, float* __restrict__ As, float* __restrict__ Ad,
                   int N) {
    constexpr int S = K + 4;        // padded LDS row stride (floats)
    constexpr int F4R = K / 4;      // float4 per row
    __shared__ float xs[32][S];
    int t = threadIdx.x;
    int block0 = blockIdx.x * 32;

    for (int i = t; i < 32 * F4R; i += 256) {
        int row = i / F4R, c4 = i - row * F4R;
        int node = block0 + row;
        float4 v = (node < N) ? *(const float4*)(X + (size_t)node * K + c4 * 4)
                              : make_float4(0.f, 0.f, 0.f, 0.f);
        *(float4*)(&xs[row][c4 * 4]) = v;
    }
    __syncthreads();

    int wave = t >> 6, lane = t & 63;
    int jj = lane >> 4, cc = lane & 15;
    int r0 = wave * 8 + jj * 2;     // local node pair
    int base = block0 + r0;

    float4 o0 = make_float4(0.f, 0.f, 0.f, 0.f);
    float4 o1 = make_float4(0.f, 0.f, 0.f, 0.f);

    const float* wp = W + cc * 4;
#pragma unroll 2
    for (int k = 0; k < K; k += 4) {
        float4 w0 = *(const float4*)(wp + (size_t)(k + 0) * 64);
        float4 w1 = *(const float4*)(wp + (size_t)(k + 1) * 64);
        float4 w2 = *(const float4*)(wp + (size_t)(k + 2) * 64);
        float4 w3 = *(const float4*)(wp + (size_t)(k + 3) * 64);
        float4 m0 = *(const float4*)(&xs[r0][k]);
        float4 m1 = *(const float4*)(&xs[r0 + 1][k]);

        o0.x = fmaf(m0.x, w0.x, o0.x);
        o0.y = fmaf(m0.x, w0.y, o0.y);
        o0.z = fmaf(m0.x, w0.z, o0.z);
        o0.w = fmaf(m0.x, w0.w, o0.w);
        o0.x = fmaf(m0.y, w1.x, o0.x);
        o0.y = fmaf(m0.y, w1.y, o0.y);
        o0.z = fmaf(m0.y, w1.z, o0.z);
        o0.w = fmaf(m0.y, w1.w, o0.w);
        o0.x = fmaf(m0.z, w2.x, o0.x);
        o0.y = fmaf(m0.z, w2.y, o0.y);
        o0.z = fmaf(m0.z, w2.z, o0.z);
        o0.w = fmaf(m0.z, w2.w, o0.w);
        o0.x = fmaf(m0.w, w3.x, o0.x);
        o0.y = fmaf(m0.w, w3.y, o0.y);
        o0.z = fmaf(m0.w, w3.z, o0.z);
        o0.w = fmaf(m0.w, w3.w, o0.w);

        o1.x = fmaf(m1.x, w0.x, o1.x);
        o1.y = fmaf(m1.x, w0.y, o1.y);
        o1.z = fmaf(m1.x, w0.z, o1.z);
        o1.w = fmaf(m1.x, w0.w, o1.w);
        o1.x = fmaf(m1.y, w1.x, o1.x);
        o1.y = fmaf(m1.y, w1.y, o1.y);
        o1.z = fmaf(m1.y, w1.z, o1.z);
        o1.w = fmaf(m1.y, w1.w, o1.w);
        o1.x = fmaf(m1.z, w2.x, o1.x);
        o1.y = fmaf(m1.z, w2.y, o1.y);
        o1.z = fmaf(m1.z, w2.z, o1.z);
        o1.w = fmaf(m1.z, w2.w, o1.w);
        o1.x = fmaf(m1.w, w3.x, o1.x);
        o1.y = fmaf(m1.w, w3.y, o1.y);
        o1.z = fmaf(m1.w, w3.z, o1.z);
        o1.w = fmaf(m1.w, w3.w, o1.w);
    }

    float4 av = *(const float4*)(a_src + cc * 4);
    float4 dv = *(const float4*)(a_dst + cc * 4);

    if (base < N) {
        union { __half2 h[2]; uint2 u; } pk;
        pk.h[0] = __floats2half2_rn(o0.x, o0.y);
        pk.h[1] = __floats2half2_rn(o0.z, o0.w);
        *(uint2*)(XWh + (size_t)base * 64 + cc * 4) = pk.u;
        float s = o0.x * av.x + o0.y * av.y + o0.z * av.z + o0.w * av.w;
        float d = o0.x * dv.x + o0.y * dv.y + o0.z * dv.z + o0.w * dv.w;
        s += __shfl_xor(s, 1);
        d += __shfl_xor(d, 1);
        if ((cc & 1) == 0) {
            As[base * 8 + (cc >> 1)] = s;
            Ad[base * 8 + (cc >> 1)] = d;
        }
    }
    if (base + 1 < N) {
        union { __half2 h[2]; uint2 u; } pk;
        pk.h[0] = __floats2half2_rn(o1.x, o1.y);
        pk.h[1] = __floats2half2_rn(o1.z, o1.w);
        *(uint2*)(XWh + (size_t)(base + 1) * 64 + cc * 4) = pk.u;
        float s = o1.x * av.x + o1.y * av.y + o1.z * av.z + o1.w * av.w;
        float d = o1.x * dv.x + o1.y * dv.y + o1.z * dv.z + o1.w * dv.w;
        s += __shfl_xor(s, 1);
        d += __shfl_xor(d, 1);
        if ((cc & 1) == 0) {
            As[(base + 1) * 8 + (cc >> 1)] = s;
            Ad[(base + 1) * 8 + (cc >> 1)] = d;
        }
    }
}

// ---------------- Aggregation v7 (layers 1 & 2: H=8, C=8) ------------------
// 2-deep pipeline; per chunk: ONE coalesced adj load per 8-edge half (lanes
// hold adj[b+eP] / adj[b+8+eP]); gather-row indices obtained via __shfl from
// those registers (DS pipe) instead of 16 broadcast VMEM loads. Full chunks
// (KK < TF) take an unclamped fast path (wave-uniform branch); only the last
// partial chunk clamps + masks.

#define AROW(S, J, EREG)                                                       \
    {                                                                          \
        int ri_ = __shfl((EREG), (((2 * (J)) & 7) + r) * 8);                   \
        g##S##J = XW[(size_t)ri_ * 32 + c2];                                   \
    }

#define AISSUE_F(S, KK)                                                        \
    {                                                                          \
        int b_ = beg + ((KK) << 4);                                            \
        ea##S = adj[b_ + eP];                                                  \
        eb##S = adj[b_ + 8 + eP];                                              \
        asa##S = As[(size_t)ea##S * 8 + hP];                                   \
        asb##S = As[(size_t)eb##S * 8 + hP];                                   \
        AROW(S, 0, ea##S) AROW(S, 1, ea##S) AROW(S, 2, ea##S) AROW(S, 3, ea##S)\
        AROW(S, 4, eb##S) AROW(S, 5, eb##S) AROW(S, 6, eb##S) AROW(S, 7, eb##S)\
    }

#define AISSUE_C(S, KK)                                                        \
    {                                                                          \
        int b_ = beg + ((KK) << 4);                                            \
        int lim_ = end - 1;                                                    \
        int ia_ = b_ + eP; ia_ = (ia_ < lim_) ? ia_ : lim_;                    \
        int ib_ = b_ + 8 + eP; ib_ = (ib_ < lim_) ? ib_ : lim_;                \
        ea##S = adj[ia_];                                                      \
        eb##S = adj[ib_];                                                      \
        asa##S = As[(size_t)ea##S * 8 + hP];                                   \
        asb##S = As[(size_t)eb##S * 8 + hP];                                   \
        AROW(S, 0, ea##S) AROW(S, 1, ea##S) AROW(S, 2, ea##S) AROW(S, 3, ea##S)\
        AROW(S, 4, eb##S) AROW(S, 5, eb##S) AROW(S, 6, eb##S) AROW(S, 7, eb##S)\
    }

#define APC(S, J, P)                                                           \
    {                                                                          \
        float2 xv_ = __half22float2(g##S##J);                                  \
        float pk_ = __shfl((P), (((2 * (J)) & 7) + r) * 8 + hA);               \
        accx = fmaf(pk_, xv_.x, accx);                                         \
        accy = fmaf(pk_, xv_.y, accy);                                         \
    }

#define ACONS_F(S, KK)                                                         \
    {                                                                          \
        float pa_ = __expf(lrelu(asa##S + adp));                               \
        float pb_ = __expf(lrelu(asb##S + adp));                               \
        den_part += pa_ + pb_;                                                 \
        APC(S, 0, pa_) APC(S, 1, pa_) APC(S, 2, pa_) APC(S, 3, pa_)            \
        APC(S, 4, pb_) APC(S, 5, pb_) APC(S, 6, pb_) APC(S, 7, pb_)            \
    }

#define ACONS_C(S, KK)                                                         \
    {                                                                          \
        int b_ = beg + ((KK) << 4);                                            \
        float pa_ = (b_ + eP < end) ? __expf(lrelu(asa##S + adp)) : 0.f;       \
        float pb_ = (b_ + 8 + eP < end) ? __expf(lrelu(asb##S + adp)) : 0.f;   \
        den_part += pa_ + pb_;                                                 \
        APC(S, 0, pa_) APC(S, 1, pa_) APC(S, 2, pa_) APC(S, 3, pa_)            \
        APC(S, 4, pb_) APC(S, 5, pb_) APC(S, 6, pb_) APC(S, 7, pb_)            \
    }

#define AI(S, KK) { if ((KK) < TF) AISSUE_F(S, KK) else AISSUE_C(S, KK) }
#define AC(S, KK) { if ((KK) < TF) ACONS_F(S, KK) else ACONS_C(S, KK) }

template <bool WITH_A3, bool HALF_OUT>
__global__ __launch_bounds__(256)
void agg_h8c8_v7(const __half2* __restrict__ XW, const float* __restrict__ As,
                 const float* __restrict__ Ad, const int* __restrict__ row_ptr,
                 const int* __restrict__ adj, const float* __restrict__ bias,
                 void* __restrict__ OUTv,
                 const float* __restrict__ w_as, const float* __restrict__ w_ad,
                 float* __restrict__ As3, float* __restrict__ Ad3, int N) {
    int wave = threadIdx.x >> 6, lane = threadIdx.x & 63;
    int node = blockIdx.x * 4 + wave;
    if (node >= N) return;
    int beg = row_ptr[node], end = row_ptr[node + 1];
    int eP = lane >> 3, hP = lane & 7;     // p-phase coords
    int r = lane >> 5, c2 = lane & 31;     // acc-phase coords
    int hA = c2 >> 2;                      // head of channels (2c2, 2c2+1)
    float adp = Ad[node * 8 + hP];

    float den_part = 0.f;
    float accx = 0.f, accy = 0.f;
    float asaA, asbA, asaB, asbB;
    int eaA, ebA, eaB, ebB;
    __half2 gA0, gA1, gA2, gA3, gA4, gA5, gA6, gA7;
    __half2 gB0, gB1, gB2, gB3, gB4, gB5, gB6, gB7;

    int deg = end - beg;             // >= 1 (self-loops)
    int TF = deg >> 4;               // full chunks
    int T = (deg + 15) >> 4;         // total chunks >= 1
    AI(A, 0)
    int k = 0;
    while (k + 2 < T) {
        AI(B, k + 1)
        AC(A, k)
        AI(A, k + 2)
        AC(B, k + 1)
        k += 2;
    }
    if (k + 1 < T) {
        AI(B, k + 1)
        AC(A, k)
        AC(B, k + 1)
    } else {
        AC(A, k)
    }

    // combine edge-parity halves: lane i and i+32 hold the same channels
    accx += __shfl_xor(accx, 32);
    accy += __shfl_xor(accy, 32);
    // den: sum over e-slots, lane holds den[lane&7]; route den[hA] to acc lane
    den_part += __shfl_xor(den_part, 8);
    den_part += __shfl_xor(den_part, 16);
    den_part += __shfl_xor(den_part, 32);
    float den = __shfl(den_part, hA);

    float rden = 1.f / (den + 1e-16f);
    float vx = fmaxf(accx * rden + bias[c2 * 2], 0.f);
    float vy = fmaxf(accy * rden + bias[c2 * 2 + 1], 0.f);
    if (r == 0) {
        if (HALF_OUT) ((__half2*)OUTv)[(size_t)node * 32 + c2] = __floats2half2_rn(vx, vy);
        else          ((float2*)OUTv)[(size_t)node * 32 + c2] = make_float2(vx, vy);
    }

    if (WITH_A3) {
        // all lanes hold channel sums (lane i == lane i+32); reduce lanes 0..31
        float s3v = vx * w_as[c2 * 2] + vy * w_as[c2 * 2 + 1];
        float d3v = vx * w_ad[c2 * 2] + vy * w_ad[c2 * 2 + 1];
#pragma unroll
        for (int m = 1; m <= 16; m <<= 1) {
            s3v += __shfl_xor(s3v, m);
            d3v += __shfl_xor(d3v, m);
        }
        if (lane == 0) {
            As3[node] = s3v;
            Ad3[node] = d3v;
        }
    }
}

// ---------------- Layer 3 aggregation v7 (H=1, 64 cols) --------------------
// eP3 = lane&15 covers all 16 chunk edges in ONE coalesced adj load; row
// indices via __shfl(ea3, 2J+r); p masked per-lane in the partial chunk.

#define BROW(S, J)                                                             \
    {                                                                          \
        int ri_ = __shfl(ea3##S, 2 * (J) + r);                                 \
        q##S##J = H2[(size_t)ri_ * 32 + c2];                                   \
    }

#define BISSUE_F(S, KK)                                                        \
    {                                                                          \
        int b_ = beg + ((KK) << 4);                                            \
        ea3##S = adj[b_ + eP3];                                                \
        as3##S = As3[ea3##S];                                                  \
        BROW(S, 0) BROW(S, 1) BROW(S, 2) BROW(S, 3)                            \
        BROW(S, 4) BROW(S, 5) BROW(S, 6) BROW(S, 7)                            \
    }

#define BISSUE_C(S, KK)                                                        \
    {                                                                          \
        int b_ = beg + ((KK) << 4);                                            \
        int lim_ = end - 1;                                                    \
        int ie_ = b_ + eP3; ie_ = (ie_ < lim_) ? ie_ : lim_;                   \
        ea3##S = adj[ie_];                                                     \
        as3##S = As3[ea3##S];                                                  \
        BROW(S, 0) BROW(S, 1) BROW(S, 2) BROW(S, 3)                            \
        BROW(S, 4) BROW(S, 5) BROW(S, 6) BROW(S, 7)                            \
    }

#define BPC(S, J, P)                                                           \
    {                                                                          \
        float2 xv_ = __half22float2(q##S##J);                                  \
        float pk_ = __shfl((P), 2 * (J) + r);                                  \
        accx = fmaf(pk_, xv_.x, accx);                                         \
        accy = fmaf(pk_, xv_.y, accy);                                         \
    }

#define BCONS_F(S, KK)                                                         \
    {                                                                          \
        float p_ = __expf(lrelu(as3##S + ad));                                 \
        den_part += p_;                                                        \
        BPC(S, 0, p_) BPC(S, 1, p_) BPC(S, 2, p_) BPC(S, 3, p_)                \
        BPC(S, 4, p_) BPC(S, 5, p_) BPC(S, 6, p_) BPC(S, 7, p_)                \
    }

#define BCONS_C(S, KK)                                                         \
    {                                                                          \
        int b_ = beg + ((KK) << 4);                                            \
        float p_ = (b_ + eP3 < end) ? __expf(lrelu(as3##S + ad)) : 0.f;        \
        den_part += p_;                                                        \
        BPC(S, 0, p_) BPC(S, 1, p_) BPC(S, 2, p_) BPC(S, 3, p_)                \
        BPC(S, 4, p_) BPC(S, 5, p_) BPC(S, 6, p_) BPC(S, 7, p_)                \
    }

#define BI(S, KK) { if ((KK) < TF) BISSUE_F(S, KK) else BISSUE_C(S, KK) }
#define BC(S, KK) { if ((KK) < TF) BCONS_F(S, KK) else BCONS_C(S, KK) }

__global__ __launch_bounds__(256)
void agg3msg_v7(const __half2* __restrict__ H2, const float* __restrict__ As3,
                const float* __restrict__ Ad3, const int* __restrict__ row_ptr,
                const int* __restrict__ adj, float* __restrict__ MSG, int N) {
    int wave = threadIdx.x >> 6, lane = threadIdx.x & 63;
    int node = blockIdx.x * 4 + wave;
    if (node >= N) return;
    int beg = row_ptr[node], end = row_ptr[node + 1];
    float ad = Ad3[node];
    int eP3 = lane & 15;
    int r = lane >> 5, c2 = lane & 31;

    float den_part = 0.f;
    float accx = 0.f, accy = 0.f;
    float as3A, as3B;
    int ea3A, ea3B;
    __half2 qA0, qA1, qA2, qA3, qA4, qA5, qA6, qA7;
    __half2 qB0, qB1, qB2, qB3, qB4, qB5, qB6, qB7;

    int deg = end - beg;
    int TF = deg >> 4;
    int T = (deg + 15) >> 4;
    BI(A, 0)
    int k = 0;
    while (k + 2 < T) {
        BI(B, k + 1)
        BC(A, k)
        BI(A, k + 2)
        BC(B, k + 1)
        k += 2;
    }
    if (k + 1 < T) {
        BI(B, k + 1)
        BC(A, k)
        BC(B, k + 1)
    } else {
        BC(A, k)
    }

    accx += __shfl_xor(accx, 32);
    accy += __shfl_xor(accy, 32);
    den_part += __shfl_xor(den_part, 1);
    den_part += __shfl_xor(den_part, 2);
    den_part += __shfl_xor(den_part, 4);
    den_part += __shfl_xor(den_part, 8);  // every lane: full den
    float rden = 1.f / (den_part + 1e-16f);
    if (r == 0) {
        ((float2*)MSG)[(size_t)node * 32 + c2] = make_float2(accx * rden, accy * rden);
    }
}

// ---------------- gemm3 v3: OUT = softmax_pairs(relu(MSG @ W3 + b3)) -------

#define G3FMA(WR0, WR1, WR2, WR3, J, KK)                                       \
    {                                                                          \
        float4 m_ = *(const float4*)(sh + wave * 512 + (J) * 64 + (KK));       \
        o[J][0] = fmaf(m_.x, (WR0).x, o[J][0]);                                \
        o[J][1] = fmaf(m_.x, (WR0).y, o[J][1]);                                \
        o[J][2] = fmaf(m_.x, (WR0).z, o[J][2]);                                \
        o[J][3] = fmaf(m_.x, (WR0).w, o[J][3]);                                \
        o[J][0] = fmaf(m_.y, (WR1).x, o[J][0]);                                \
        o[J][1] = fmaf(m_.y, (WR1).y, o[J][1]);                                \
        o[J][2] = fmaf(m_.y, (WR1).z, o[J][2]);                                \
        o[J][3] = fmaf(m_.y, (WR1).w, o[J][3]);                                \
        o[J][0] = fmaf(m_.z, (WR2).x, o[J][0]);                                \
        o[J][1] = fmaf(m_.z, (WR2).y, o[J][1]);                                \
        o[J][2] = fmaf(m_.z, (WR2).z, o[J][2]);                                \
        o[J][3] = fmaf(m_.z, (WR2).w, o[J][3]);                                \
        o[J][0] = fmaf(m_.w, (WR3).x, o[J][0]);                                \
        o[J][1] = fmaf(m_.w, (WR3).y, o[J][1]);                                \
        o[J][2] = fmaf(m_.w, (WR3).z, o[J][2]);                                \
        o[J][3] = fmaf(m_.w, (WR3).w, o[J][3]);                                \
    }

#define GWLD(S, KK)                                                            \
    {                                                                          \
        const float* wp_ = W3p + (size_t)(KK) * 244 + c0;                      \
        w##S##0 = *(const float4*)(wp_);                                       \
        w##S##1 = *(const float4*)(wp_ + 244);                                 \
        w##S##2 = *(const float4*)(wp_ + 488);                                 \
        w##S##3 = *(const float4*)(wp_ + 732);                                 \
    }

#define GWCONS(S, KK)                                                          \
    G3FMA(w##S##0, w##S##1, w##S##2, w##S##3, 0, KK)                           \
    G3FMA(w##S##0, w##S##1, w##S##2, w##S##3, 1, KK)                           \
    G3FMA(w##S##0, w##S##1, w##S##2, w##S##3, 2, KK)                           \
    G3FMA(w##S##0, w##S##1, w##S##2, w##S##3, 3, KK)                           \
    G3FMA(w##S##0, w##S##1, w##S##2, w##S##3, 4, KK)                           \
    G3FMA(w##S##0, w##S##1, w##S##2, w##S##3, 5, KK)                           \
    G3FMA(w##S##0, w##S##1, w##S##2, w##S##3, 6, KK)                           \
    G3FMA(w##S##0, w##S##1, w##S##2, w##S##3, 7, KK)

__global__ __launch_bounds__(256)
void gemm3_v3(const float* __restrict__ MSG, const float* __restrict__ W3p,
              const float* __restrict__ bias, float* __restrict__ OUT, int N) {
    __shared__ float sh[32 * 244];  // 31232 B
    int t = threadIdx.x;
    int wave = t >> 6, lane = t & 63;
    int block0 = blockIdx.x * 32;

    // stage MSG into msh region (per-wave; same-wave LDS RAW, DS in-order)
#pragma unroll
    for (int j = 0; j < 8; ++j) {
        int node = block0 + wave * 8 + j;
        sh[wave * 512 + j * 64 + lane] =
            (node < N) ? MSG[(size_t)node * 64 + lane] : 0.f;
    }

    int c0 = lane * 4;  // lanes 0..60 carry channels; 61-63 idle in compute
    float o[8][4];
    if (c0 < 242) {
#pragma unroll
        for (int j = 0; j < 8; ++j)
#pragma unroll
            for (int q = 0; q < 4; ++q) o[j][q] = 0.f;

        float4 wA0, wA1, wA2, wA3, wB0, wB1, wB2, wB3;
        GWLD(A, 0)
#pragma unroll
        for (int k = 0; k < 64; k += 8) {
            GWLD(B, k + 4)
            GWCONS(A, k)
            if (k + 8 < 64) { GWLD(A, k + 8) }
            GWCONS(B, k + 4)
        }
    }
    __syncthreads();  // all msh reads complete before tile overwrites

    if (c0 < 242) {
        float b0 = bias[c0], b1v = bias[c0 + 1];
        float b2v = (c0 + 2 < 242) ? bias[c0 + 2] : 0.f;
        float b3v = (c0 + 3 < 242) ? bias[c0 + 3] : 0.f;
#pragma unroll
        for (int j = 0; j < 8; ++j) {
            float v0 = fmaxf(o[j][0] + b0, 0.f);
            float v1 = fmaxf(o[j][1] + b1v, 0.f);
            float m01 = fmaxf(v0, v1);
            float e0 = __expf(v0 - m01), e1 = __expf(v1 - m01);
            float r01 = 1.f / (e0 + e1);
            float q0 = e0 * r01, q1 = e1 * r01, q2 = 0.f, q3 = 0.f;
            if (c0 + 2 < 242) {
                float v2 = fmaxf(o[j][2] + b2v, 0.f);
                float v3 = fmaxf(o[j][3] + b3v, 0.f);
                float m23 = fmaxf(v2, v3);
                float e2 = __expf(v2 - m23), e3 = __expf(v3 - m23);
                float r23 = 1.f / (e2 + e3);
                q2 = e2 * r23;
                q3 = e3 * r23;
            }
            int jn = wave * 8 + j;
            // byte offset jn*976 + lane*16: 16B-aligned (976 % 16 == 0)
            *(float4*)(&sh[jn * 244 + c0]) = make_float4(q0, q1, q2, q3);
        }
    }
    __syncthreads();

    // dense coalesced copy: block's rows are contiguous in OUT
    int rows = N - block0;
    if (rows > 32) rows = 32;
    int nf = rows * 242;
    size_t gbase = (size_t)block0 * 242;
    for (int f = t; f < nf; f += 256) {
        int row = f / 242;           // compile-time-constant divisor -> magic mul
        int col = f - row * 242;
        OUT[gbase + f] = sh[row * 244 + col];
    }
}

// ---------------- launch ----------------

extern "C" void kernel_launch(void* const* d_in, const int* in_sizes, int n_in,
                              void* d_out, int out_size, void* d_ws, size_t ws_size,
                              hipStream_t stream) {
    const float* x   = (const float*)d_in[0];
    const void*  ei  = d_in[1];
    const float* W1  = (const float*)d_in[2];
    const float* a1s = (const float*)d_in[3];
    const float* a1d = (const float*)d_in[4];
    const float* b1  = (const float*)d_in[5];
    const float* W2  = (const float*)d_in[6];
    const float* a2s = (const float*)d_in[7];
    const float* a2d = (const float*)d_in[8];
    const float* b2  = (const float*)d_in[9];
    const float* W3  = (const float*)d_in[10];
    const float* a3s = (const float*)d_in[11];
    const float* a3d = (const float*)d_in[12];
    const float* b3  = (const float*)d_in[13];
    float* out = (float*)d_out;

    const int N = in_sizes[0] / 128;  // 50000
    const int E = in_sizes[1] / 2;    // 800000

    char* w = (char*)d_ws;
    auto alloc = [&](size_t bytes) {
        char* p = w;
        w += (bytes + 255) & ~(size_t)255;
        return p;
    };
    int*   flag    = (int*)alloc(4);
    int*   row_ptr = (int*)alloc(((size_t)N + 1) * 4);
    int*   adj     = (int*)alloc((size_t)(E + N) * 4);
    int*   btot    = (int*)alloc(256 * 4);
    int*   bbase   = (int*)alloc(257 * 4);
    float* As      = (float*)alloc((size_t)N * 8 * 4);
    float* Ad      = (float*)alloc((size_t)N * 8 * 4);
    float* As3     = (float*)alloc((size_t)N * 4);
    float* Ad3     = (float*)alloc((size_t)N * 4);
    float* w_as    = (float*)alloc(64 * 4);
    float* w_ad    = (float*)alloc(64 * 4);
    float* W3p     = (float*)alloc((size_t)64 * 244 * 4);
    float* bufA    = (float*)alloc((size_t)N * 64 * 4);
    float* bufB    = (float*)alloc((size_t)N * 64 * 4);
    // CSR scratch aliased into bufA (12.8MB): part 6.8MB @0, blkhist 256KB @7MB,
    // blkoff 256KB @7.25MB. All dead before gemm1 first writes bufA.
    int2*   part    = (int2*)bufA;
    int*    blkhist = (int*)((char*)bufA + (size_t)7 * 1024 * 1024);
    int*    blkoff  = (int*)((char*)bufA + (size_t)7 * 1024 * 1024 + 256 * 1024);
    // fp16 buffers aliased into bufA (lifetimes disjoint):
    //   XW1h @ bufA[0:6.4e6)        (gemm1 -> agg1)
    //   XW2h @ bufA[6.4e6:12.8e6)   (gemm2 -> agg2)
    //   h2h  @ bufA[0:6.4e6)        (agg2 -> agg3; XW1h dead)
    __half* XW1h = (__half*)bufA;
    __half* XW2h = (__half*)((char*)bufA + (size_t)N * 64 * 2);
    __half* h2h  = (__half*)bufA;
    float*  msg  = bufB;  // h1 dead after gemm2

    int tot  = E + N;                       // 850000
    int nblk = (tot + CH - 1) / CH;         // 208 <= 256
    int nb   = (N + 255) >> 8;              // 196 <= 256

    // CSR build (bucketed counting sort; includes self-loops)
    detect_kernel<<<1, 64, 0, stream>>>((const int*)ei, flag);
    zero_btot_kernel<<<1, 256, 0, stream>>>(btot);
    histA_kernel<<<nblk, 256, 0, stream>>>(ei, flag, blkhist, btot, E, N);
    bucket_scan_kernel<<<1, 256, 0, stream>>>(btot, bbase, nb, tot);
    blk_scan_kernel<<<nb, 256, 0, stream>>>(blkhist, bbase, blkoff, nblk);
    partC_kernel<<<nblk, 256, 0, stream>>>(ei, flag, blkoff, part, E, N);
    csrD_kernel<<<nb, 256, 0, stream>>>(part, bbase, row_ptr, adj, N);
    w3a_kernel<<<1, 128, 0, stream>>>(W3, a3s, a3d, w_as, w_ad);
    w3pad_kernel<<<(64 * 244 + 255) / 256, 256, 0, stream>>>(W3, W3p);

    int nb4 = (N + 3) / 4;
    int nb32 = (N + 31) / 32;

    // Layer 1: x -> XW1h (fp16), agg -> bufB (h1 fp32)
    gemm_alpha_v5<128><<<nb32, 256, 0, stream>>>(x, W1, a1s, a1d, XW1h, As, Ad, N);
    agg_h8c8_v7<false, false><<<nb4, 256, 0, stream>>>((const __half2*)XW1h, As, Ad,
                                                       row_ptr, adj, b1, bufB,
                                                       nullptr, nullptr,
                                                       nullptr, nullptr, N);
    // Layer 2: bufB (fp32) -> XW2h (fp16), agg -> h2h (fp16) + As3/Ad3
    gemm_alpha_v5<64><<<nb32, 256, 0, stream>>>(bufB, W2, a2s, a2d, XW2h, As, Ad, N);
    agg_h8c8_v7<true, true><<<nb4, 256, 0, stream>>>((const __half2*)XW2h, As, Ad,
                                                     row_ptr, adj, b2, h2h,
                                                     w_as, w_ad, As3, Ad3, N);
    // Layer 3: h2h (fp16) -> msg (fp32, bufB), then gemm3 v3 -> out
    agg3msg_v7<<<nb4, 256, 0, stream>>>((const __half2*)h2h, As3, Ad3, row_ptr, adj,
                                        msg, N);
    gemm3_v3<<<nb32, 256, 0, stream>>>(msg, W3p, b3, out, N);
}